// Round 1
// baseline (4415.548 us; speedup 1.0000x reference)
//
#include <hip/hip_runtime.h>
#include <math.h>

#define B_   2
#define L_   2048
#define D_   768
#define DI_  1536
#define S_   16
#define R_   48
#define M_   (B_*L_)   // 4096 tokens

__device__ __forceinline__ float siluf(float x) { return x / (1.f + __expf(-x)); }

// ---------------------------------------------------------------------------
// Generic C = A @ W.T   (A: MxK row-major lda, W: NxK row-major ldw)
// EPI 0: C = acc ; EPI 1: C = softplus(acc + bias[n]) ; EPI 2: C += acc
// ---------------------------------------------------------------------------
template<int EPI>
__global__ __launch_bounds__(256) void gemm_nt(
    const float* __restrict__ A, int lda,
    const float* __restrict__ W, int ldw,
    float* __restrict__ C, int ldc,
    const float* __restrict__ bias,
    int M, int N, int K)
{
    __shared__ float As[64][17];
    __shared__ float Ws[64][17];
    const int tid = threadIdx.x;
    const int tx = tid & 15, ty = tid >> 4;
    const int m0 = blockIdx.y * 64, n0 = blockIdx.x * 64;
    const int lr = tid >> 2;          // row 0..63 this thread loads
    const int lk = (tid & 3) * 4;     // k offset 0,4,8,12
    float acc[4][4] = {};

    for (int k0 = 0; k0 < K; k0 += 16) {
        {
            int m = m0 + lr;
            int n = n0 + lr;
            #pragma unroll
            for (int j = 0; j < 4; ++j) {
                int k = k0 + lk + j;
                As[lr][lk + j] = (m < M && k < K) ? A[(size_t)m * lda + k] : 0.f;
                Ws[lr][lk + j] = (n < N && k < K) ? W[(size_t)n * ldw + k] : 0.f;
            }
        }
        __syncthreads();
        #pragma unroll
        for (int kk = 0; kk < 16; ++kk) {
            float a[4], w[4];
            #pragma unroll
            for (int i = 0; i < 4; ++i) a[i] = As[ty * 4 + i][kk];
            #pragma unroll
            for (int j = 0; j < 4; ++j) w[j] = Ws[tx * 4 + j][kk];
            #pragma unroll
            for (int i = 0; i < 4; ++i)
                #pragma unroll
                for (int j = 0; j < 4; ++j)
                    acc[i][j] += a[i] * w[j];
        }
        __syncthreads();
    }

    #pragma unroll
    for (int i = 0; i < 4; ++i) {
        int m = m0 + ty * 4 + i;
        if (m >= M) continue;
        #pragma unroll
        for (int j = 0; j < 4; ++j) {
            int n = n0 + tx * 4 + j;
            if (n >= N) continue;
            float v = acc[i][j];
            if (EPI == 1) {
                v += bias[n];
                v = (v > 20.f) ? v : log1pf(__expf(v));   // softplus
            }
            size_t idx = (size_t)m * ldc + n;
            if (EPI == 2) v += C[idx];
            C[idx] = v;
        }
    }
}

// ---------------------------------------------------------------------------
// C = A @ B   (A: MxK row-major lda, B: KxN row-major ldb) — for Wc precompute
// ---------------------------------------------------------------------------
__global__ __launch_bounds__(256) void gemm_nn(
    const float* __restrict__ A, int lda,
    const float* __restrict__ Bm, int ldb,
    float* __restrict__ C, int ldc,
    int M, int N, int K)
{
    __shared__ float As[64][17];
    __shared__ float Bs[16][65];
    const int tid = threadIdx.x;
    const int tx = tid & 15, ty = tid >> 4;
    const int m0 = blockIdx.y * 64, n0 = blockIdx.x * 64;
    const int lr = tid >> 2, lk = (tid & 3) * 4;   // A loader
    const int br = tid >> 4, bn = (tid & 15) * 4;  // B loader
    float acc[4][4] = {};

    for (int k0 = 0; k0 < K; k0 += 16) {
        {
            int m = m0 + lr;
            #pragma unroll
            for (int j = 0; j < 4; ++j) {
                int k = k0 + lk + j;
                As[lr][lk + j] = (m < M && k < K) ? A[(size_t)m * lda + k] : 0.f;
            }
            int k = k0 + br;
            #pragma unroll
            for (int j = 0; j < 4; ++j) {
                int n = n0 + bn + j;
                Bs[br][bn + j] = (k < K && n < N) ? Bm[(size_t)k * ldb + n] : 0.f;
            }
        }
        __syncthreads();
        #pragma unroll
        for (int kk = 0; kk < 16; ++kk) {
            float a[4], w[4];
            #pragma unroll
            for (int i = 0; i < 4; ++i) a[i] = As[ty * 4 + i][kk];
            #pragma unroll
            for (int j = 0; j < 4; ++j) w[j] = Bs[kk][tx * 4 + j];
            #pragma unroll
            for (int i = 0; i < 4; ++i)
                #pragma unroll
                for (int j = 0; j < 4; ++j)
                    acc[i][j] += a[i] * w[j];
        }
        __syncthreads();
    }

    #pragma unroll
    for (int i = 0; i < 4; ++i) {
        int m = m0 + ty * 4 + i;
        if (m >= M) continue;
        #pragma unroll
        for (int j = 0; j < 4; ++j) {
            int n = n0 + tx * 4 + j;
            if (n >= N) continue;
            C[(size_t)m * ldc + n] = acc[i][j];
        }
    }
}

// ---------------------------------------------------------------------------
// Depthwise causal conv (K=4) + bias + SiLU.
// fwd (rev=0): out[l] = sum_j w[j]*x[l+j-3] ; bwd (rev=1): out[l] = sum_j w[j]*x[l+3-j]
// ---------------------------------------------------------------------------
__global__ __launch_bounds__(256) void conv_silu_k(
    const float* __restrict__ xc, const float* __restrict__ cw,
    const float* __restrict__ cb, float* __restrict__ out, int rev)
{
    int idx = blockIdx.x * 256 + threadIdx.x;
    if (idx >= B_ * L_ * DI_) return;
    int d = idx % DI_;
    int l = (idx / DI_) % L_;
    int b = idx / (DI_ * L_);
    float acc = cb[d];
    #pragma unroll
    for (int j = 0; j < 4; ++j) {
        int ll = rev ? (l + 3 - j) : (l + j - 3);
        if (ll >= 0 && ll < L_)
            acc += cw[d * 4 + j] * xc[((size_t)b * L_ + ll) * DI_ + d];
    }
    out[idx] = siluf(acc);
}

// ---------------------------------------------------------------------------
// Selective scan, both directions in one launch (blockIdx.z = dir).
// 16 lanes per (b,d) channel (one per state s); 16 channels per 256-thread block.
// Writes y' = (y_scan + xcv*Dp) * silu(z) in-place over xcv.
// ---------------------------------------------------------------------------
__global__ __launch_bounds__(256) void scan_k(
    const float* __restrict__ xcv_f, const float* __restrict__ z_f,
    const float* __restrict__ dt_f,  const float* __restrict__ dbc_f,
    const float* __restrict__ Alog_f, const float* __restrict__ Dp_f, float* __restrict__ yp_f,
    const float* __restrict__ xcv_b, const float* __restrict__ z_b,
    const float* __restrict__ dt_b,  const float* __restrict__ dbc_b,
    const float* __restrict__ Alog_b, const float* __restrict__ Dp_b, float* __restrict__ yp_b)
{
    const int dir = blockIdx.z;
    const float* xcv = dir ? xcv_b : xcv_f;
    const float* z   = dir ? z_b   : z_f;
    const float* dt  = dir ? dt_b  : dt_f;
    const float* dbc = dir ? dbc_b : dbc_f;
    const float* Alog= dir ? Alog_b: Alog_f;
    const float* Dp  = dir ? Dp_b  : Dp_f;
    float* yp        = dir ? yp_b  : yp_f;

    const int g = threadIdx.x >> 4;         // channel group in block, 0..15
    const int s = threadIdx.x & 15;         // state index
    const int d = blockIdx.x * 16 + g;      // 0..1535
    const int b = blockIdx.y;

    const float A   = -__expf(Alog[d * S_ + s]);
    const float Dpv = Dp[d];
    float h = 0.f;

    for (int t = 0; t < L_; ++t) {
        int pos = dir ? (L_ - 1 - t) : t;
        size_t rowo = (size_t)b * L_ + pos;
        float dtv = dt[rowo * DI_ + d];
        float xv  = xcv[rowo * DI_ + d];
        float Bv  = dbc[rowo * 80 + R_ + s];
        float Cv  = dbc[rowo * 80 + R_ + S_ + s];
        h = __expf(dtv * A) * h + dtv * Bv * xv;
        float p = h * Cv;
        p += __shfl_xor(p, 8);
        p += __shfl_xor(p, 4);
        p += __shfl_xor(p, 2);
        p += __shfl_xor(p, 1);
        if (s == 0) {
            float zv = z[rowo * DI_ + d];
            yp[rowo * DI_ + d] = (p + xv * Dpv) * siluf(zv);
        }
    }
}

// ---------------------------------------------------------------------------
// h = x + acc + proj_b ; LayerNorm over D=768
// ---------------------------------------------------------------------------
__global__ __launch_bounds__(256) void final_ln_k(
    const float* __restrict__ x, const float* __restrict__ acc,
    const float* __restrict__ proj_b, const float* __restrict__ ln_g,
    const float* __restrict__ ln_b, float* __restrict__ out)
{
    const int row = blockIdx.x;
    const size_t base = (size_t)row * D_;
    __shared__ float hbuf[D_];
    __shared__ float wsum[4], wsum2[4];
    float s1 = 0.f, s2 = 0.f;
    for (int n = threadIdx.x; n < D_; n += 256) {
        float h = x[base + n] + acc[base + n] + proj_b[n];
        hbuf[n] = h;
        s1 += h; s2 += h * h;
    }
    #pragma unroll
    for (int off = 32; off; off >>= 1) {
        s1 += __shfl_down(s1, off);
        s2 += __shfl_down(s2, off);
    }
    const int wid = threadIdx.x >> 6;
    if ((threadIdx.x & 63) == 0) { wsum[wid] = s1; wsum2[wid] = s2; }
    __syncthreads();
    if (threadIdx.x == 0) {
        float t1 = wsum[0] + wsum[1] + wsum[2] + wsum[3];
        float t2 = wsum2[0] + wsum2[1] + wsum2[2] + wsum2[3];
        float mu = t1 / D_;
        wsum[0] = mu;
        wsum2[0] = t2 / D_ - mu * mu;
    }
    __syncthreads();
    const float mu = wsum[0];
    const float inv = rsqrtf(wsum2[0] + 1e-5f);
    for (int n = threadIdx.x; n < D_; n += 256) {
        out[base + n] = (hbuf[n] - mu) * inv * ln_g[n] + ln_b[n];
    }
}

// ---------------------------------------------------------------------------
extern "C" void kernel_launch(void* const* d_in, const int* in_sizes, int n_in,
                              void* d_out, int out_size, void* d_ws, size_t ws_size,
                              hipStream_t stream)
{
    const float* x        = (const float*)d_in[0];
    const float* f_in_w   = (const float*)d_in[1];
    const float* f_conv_w = (const float*)d_in[2];
    const float* f_conv_b = (const float*)d_in[3];
    const float* f_xproj  = (const float*)d_in[4];
    const float* f_dt_w   = (const float*)d_in[5];
    const float* f_dt_bv  = (const float*)d_in[6];
    const float* f_A_log  = (const float*)d_in[7];
    const float* f_Dp     = (const float*)d_in[8];
    const float* f_out_w  = (const float*)d_in[9];
    const float* b_in_w   = (const float*)d_in[10];
    const float* b_conv_w = (const float*)d_in[11];
    const float* b_conv_b = (const float*)d_in[12];
    const float* b_xproj  = (const float*)d_in[13];
    const float* b_dt_w   = (const float*)d_in[14];
    const float* b_dt_bv  = (const float*)d_in[15];
    const float* b_A_log  = (const float*)d_in[16];
    const float* b_Dp     = (const float*)d_in[17];
    const float* b_out_w  = (const float*)d_in[18];
    const float* proj_w   = (const float*)d_in[19];
    const float* proj_b   = (const float*)d_in[20];
    const float* ln_g     = (const float*)d_in[21];
    const float* ln_b     = (const float*)d_in[22];
    float* out = (float*)d_out;
    float* ws  = (float*)d_ws;

    // workspace layout (floats)
    const size_t TOK = (size_t)M_ * DI_;       // 6291456
    float* xc_f  = ws;
    float* z_f   = xc_f  + TOK;
    float* xc_b  = z_f   + TOK;
    float* z_b   = xc_b  + TOK;
    float* xcv_f = z_b   + TOK;
    float* xcv_b = xcv_f + TOK;
    float* dbc_f = xcv_b + TOK;                //  M*80
    float* dbc_b = dbc_f + (size_t)M_ * 80;
    float* Wc_f  = dbc_b + (size_t)M_ * 80;    //  768*1536
    float* Wc_b  = Wc_f  + (size_t)D_ * DI_;
    float* accb  = Wc_b  + (size_t)D_ * DI_;   //  M*768
    float* dt_f  = xc_f;     // xc dead after conv -> reuse for dt
    float* dt_b  = xc_b;
    float* yp_f  = xcv_f;    // scan writes y' in place
    float* yp_b  = xcv_b;

    dim3 blk(256);

    // 1) xz = x @ in_w.T  (split halves)
    gemm_nt<0><<<dim3(24, 64), blk, 0, stream>>>(x, D_, f_in_w,                    D_, xc_f, DI_, nullptr, M_, DI_, D_);
    gemm_nt<0><<<dim3(24, 64), blk, 0, stream>>>(x, D_, f_in_w + (size_t)DI_ * D_, D_, z_f,  DI_, nullptr, M_, DI_, D_);
    gemm_nt<0><<<dim3(24, 64), blk, 0, stream>>>(x, D_, b_in_w,                    D_, xc_b, DI_, nullptr, M_, DI_, D_);
    gemm_nt<0><<<dim3(24, 64), blk, 0, stream>>>(x, D_, b_in_w + (size_t)DI_ * D_, D_, z_b,  DI_, nullptr, M_, DI_, D_);

    // 2) depthwise conv + SiLU
    int cb = (B_ * L_ * DI_ + 255) / 256;
    conv_silu_k<<<cb, blk, 0, stream>>>(xc_f, f_conv_w, f_conv_b, xcv_f, 0);
    conv_silu_k<<<cb, blk, 0, stream>>>(xc_b, b_conv_w, b_conv_b, xcv_b, 1);

    // 3) dbc = xcv @ xproj.T ; dt = softplus(dbc[:, :48] @ dt_w.T + dt_b)
    gemm_nt<0><<<dim3(2, 64),  blk, 0, stream>>>(xcv_f, DI_, f_xproj, DI_, dbc_f, 80, nullptr, M_, 80, DI_);
    gemm_nt<0><<<dim3(2, 64),  blk, 0, stream>>>(xcv_b, DI_, b_xproj, DI_, dbc_b, 80, nullptr, M_, 80, DI_);
    gemm_nt<1><<<dim3(24, 64), blk, 0, stream>>>(dbc_f, 80, f_dt_w, R_, dt_f, DI_, f_dt_bv, M_, DI_, R_);
    gemm_nt<1><<<dim3(24, 64), blk, 0, stream>>>(dbc_b, 80, b_dt_w, R_, dt_b, DI_, b_dt_bv, M_, DI_, R_);

    // 4) combined output weights: Wc = proj_w[:, half] @ out_w   (D x DI)
    gemm_nn<<<dim3(24, 12), blk, 0, stream>>>(proj_w,      2 * D_, f_out_w, DI_, Wc_f, DI_, D_, DI_, D_);
    gemm_nn<<<dim3(24, 12), blk, 0, stream>>>(proj_w + D_, 2 * D_, b_out_w, DI_, Wc_b, DI_, D_, DI_, D_);

    // 5) selective scan (both directions), fused y' = (y + xcv*Dp)*silu(z)
    scan_k<<<dim3(DI_ / 16, B_, 2), blk, 0, stream>>>(
        xcv_f, z_f, dt_f, dbc_f, f_A_log, f_Dp, yp_f,
        xcv_b, z_b, dt_b, dbc_b, b_A_log, b_Dp, yp_b);

    // 6) acc = yp_f @ Wc_f.T + yp_b @ Wc_b.T
    gemm_nt<0><<<dim3(12, 64), blk, 0, stream>>>(yp_f, DI_, Wc_f, DI_, accb, D_, nullptr, M_, D_, DI_);
    gemm_nt<2><<<dim3(12, 64), blk, 0, stream>>>(yp_b, DI_, Wc_b, DI_, accb, D_, nullptr, M_, D_, DI_);

    // 7) residual + LayerNorm
    final_ln_k<<<M_, blk, 0, stream>>>(x, accb, proj_b, ln_g, ln_b, out);
}

// Round 2
// 869.591 us; speedup vs baseline: 5.0777x; 5.0777x over previous
//
#include <hip/hip_runtime.h>
#include <math.h>

#define B_   2
#define L_   2048
#define D_   768
#define DI_  1536
#define S_   16
#define R_   48
#define M_   (B_*L_)   // 4096 tokens
#define NC_  16        // scan chunks
#define CL_  128       // chunk length

typedef unsigned short ushortT;
typedef __attribute__((ext_vector_type(4))) float f32x4;
typedef __attribute__((ext_vector_type(8))) short short8;

__device__ __forceinline__ float siluf(float x) { return x / (1.f + __expf(-x)); }

__device__ __forceinline__ ushortT f2bf(float f) {
    unsigned u = __float_as_uint(f);
    unsigned r = (u + 0x7FFFu + ((u >> 16) & 1u)) >> 16;
    return (ushortT)r;
}
__device__ __forceinline__ float bf2f(ushortT h) {
    return __uint_as_float(((unsigned)h) << 16);
}

__device__ __forceinline__ void stage16(const ushortT* g, ushortT* l) {
    __builtin_amdgcn_global_load_lds(
        (const __attribute__((address_space(1))) unsigned int*)g,
        (__attribute__((address_space(3))) unsigned int*)l, 16, 0, 0);
}

__device__ __forceinline__ void storeC(float* p, float v)   { *p = v; }
__device__ __forceinline__ void storeC(ushortT* p, float v) { *p = f2bf(v); }

// ---------------------------------------------------------------------------
// fp32 -> bf16 convert with optional zero-pad to ntot
// ---------------------------------------------------------------------------
__global__ __launch_bounds__(256) void f2bf_k(
    const float* __restrict__ in, ushortT* __restrict__ out, int n, int ntot)
{
    for (int i = blockIdx.x * 256 + threadIdx.x; i < ntot; i += gridDim.x * 256)
        out[i] = (i < n) ? f2bf(in[i]) : (ushortT)0;
}

// ---------------------------------------------------------------------------
// MFMA GEMM: C[M][ldc] = A[M][lda](bf16) @ W[Npad][ldw](bf16)^T
// 128x128 tile, BK=32, 4 waves (2x2), m97-style global_load_lds staging.
// M%128==0, K%32==0, grid.x covers N in 128-tiles (W rows must be padded).
// ---------------------------------------------------------------------------
template<typename OutT, bool NMASK>
__global__ __launch_bounds__(256) void mfma_nt(
    const ushortT* __restrict__ A, int lda,
    const ushortT* __restrict__ W, int ldw,
    OutT* __restrict__ C, int ldc,
    int M, int K, int Nreal)
{
    __shared__ ushortT As[128 * 32];
    __shared__ ushortT Ws[128 * 32];
    const int tid = threadIdx.x;
    const int lane = tid & 63, wid = tid >> 6;
    const int wr = wid >> 1, wc = wid & 1;
    const int m0 = blockIdx.y * 128, n0 = blockIdx.x * 128;

    f32x4 acc[4][4];
    #pragma unroll
    for (int m = 0; m < 4; ++m)
        #pragma unroll
        for (int n = 0; n < 4; ++n)
            acc[m][n] = (f32x4){0.f, 0.f, 0.f, 0.f};

    const int kq = (lane >> 4) * 8;   // k sub-offset for frags
    const int lr = lane & 15;

    for (int k0 = 0; k0 < K; k0 += 32) {
        #pragma unroll
        for (int r = 0; r < 2; ++r) {
            int off = r * 4096 + tid * 16;      // byte offset in 8KB tile
            int row = off >> 6;                 // 64B per row (32 bf16)
            int col = (off & 63) >> 1;
            int lbase = r * 2048 + wid * 512;   // ushort units, wave-uniform
            stage16(A + (size_t)(m0 + row) * lda + k0 + col, As + lbase);
            stage16(W + (size_t)(n0 + row) * ldw + k0 + col, Ws + lbase);
        }
        __syncthreads();

        short8 afr[4], bfr[4];
        #pragma unroll
        for (int m = 0; m < 4; ++m)
            afr[m] = *(const short8*)(As + (wr * 64 + m * 16 + lr) * 32 + kq);
        #pragma unroll
        for (int n = 0; n < 4; ++n)
            bfr[n] = *(const short8*)(Ws + (wc * 64 + n * 16 + lr) * 32 + kq);
        #pragma unroll
        for (int m = 0; m < 4; ++m)
            #pragma unroll
            for (int n = 0; n < 4; ++n)
                acc[m][n] = __builtin_amdgcn_mfma_f32_16x16x32_bf16(
                    afr[m], bfr[n], acc[m][n], 0, 0, 0);
        __syncthreads();
    }

    // C/D layout: col = lane&15, row = (lane>>4)*4 + reg   [m89 verified]
    #pragma unroll
    for (int m = 0; m < 4; ++m) {
        #pragma unroll
        for (int n = 0; n < 4; ++n) {
            int colg = n0 + wc * 64 + n * 16 + (lane & 15);
            if (NMASK && colg >= Nreal) continue;
            #pragma unroll
            for (int r = 0; r < 4; ++r) {
                int rowg = m0 + wr * 64 + m * 16 + (lane >> 4) * 4 + r;
                storeC(&C[(size_t)rowg * ldc + colg], acc[m][n][r]);
            }
        }
    }
}

// ---------------------------------------------------------------------------
// fp32 vector GEMM (small K): C = softplus(A @ W^T + bias) -> bf16
// A: MxK row-major lda (fp32), W: NxK row-major ldw (fp32)
// ---------------------------------------------------------------------------
__global__ __launch_bounds__(256) void gemm_dt(
    const float* __restrict__ A, int lda,
    const float* __restrict__ W, int ldw,
    ushortT* __restrict__ C, int ldc,
    const float* __restrict__ bias,
    int M, int N, int K)
{
    __shared__ float As[64][17];
    __shared__ float Ws[64][17];
    const int tid = threadIdx.x;
    const int tx = tid & 15, ty = tid >> 4;
    const int m0 = blockIdx.y * 64, n0 = blockIdx.x * 64;
    const int lr = tid >> 2;
    const int lk = (tid & 3) * 4;
    float acc[4][4] = {};

    for (int k0 = 0; k0 < K; k0 += 16) {
        int m = m0 + lr;
        int n = n0 + lr;
        #pragma unroll
        for (int j = 0; j < 4; ++j) {
            int k = k0 + lk + j;
            As[lr][lk + j] = (m < M && k < K) ? A[(size_t)m * lda + k] : 0.f;
            Ws[lr][lk + j] = (n < N && k < K) ? W[(size_t)n * ldw + k] : 0.f;
        }
        __syncthreads();
        #pragma unroll
        for (int kk = 0; kk < 16; ++kk) {
            float a[4], w[4];
            #pragma unroll
            for (int i = 0; i < 4; ++i) a[i] = As[ty * 4 + i][kk];
            #pragma unroll
            for (int j = 0; j < 4; ++j) w[j] = Ws[tx * 4 + j][kk];
            #pragma unroll
            for (int i = 0; i < 4; ++i)
                #pragma unroll
                for (int j = 0; j < 4; ++j)
                    acc[i][j] += a[i] * w[j];
        }
        __syncthreads();
    }

    #pragma unroll
    for (int i = 0; i < 4; ++i) {
        int m = m0 + ty * 4 + i;
        if (m >= M) continue;
        #pragma unroll
        for (int j = 0; j < 4; ++j) {
            int n = n0 + tx * 4 + j;
            if (n >= N) continue;
            float v = acc[i][j] + bias[n];
            v = (v > 20.f) ? v : log1pf(__expf(v));
            C[(size_t)m * ldc + n] = f2bf(v);
        }
    }
}

// ---------------------------------------------------------------------------
// Depthwise conv (K=4) + bias + SiLU. Reads xc half of xz (bf16, stride 3072),
// writes xcv bf16 [M][1536].
// ---------------------------------------------------------------------------
__global__ __launch_bounds__(256) void conv_silu_k(
    const ushortT* __restrict__ xz, const float* __restrict__ cw,
    const float* __restrict__ cb, ushortT* __restrict__ out, int rev)
{
    int idx = blockIdx.x * 256 + threadIdx.x;
    if (idx >= B_ * L_ * DI_) return;
    int d = idx % DI_;
    int l = (idx / DI_) % L_;
    int b = idx / (DI_ * L_);
    float acc = cb[d];
    #pragma unroll
    for (int j = 0; j < 4; ++j) {
        int ll = rev ? (l + 3 - j) : (l + j - 3);
        if (ll >= 0 && ll < L_)
            acc += cw[d * 4 + j] * bf2f(xz[((size_t)b * L_ + ll) * 3072 + d]);
    }
    out[idx] = f2bf(siluf(acc));
}

// ---------------------------------------------------------------------------
// Scan pass 1: per (dir,b,d,s,chunk): local scan from h=0 -> (aprod, hloc)
// block: 16 channels x 16 states; grid (96, B, 2*NC)
// ---------------------------------------------------------------------------
__global__ __launch_bounds__(256) void scan1_k(
    const ushortT* __restrict__ xcv_f, const ushortT* __restrict__ dt_f,
    const float* __restrict__ dbc_f, const float* __restrict__ Af,
    const ushortT* __restrict__ xcv_b, const ushortT* __restrict__ dt_b,
    const float* __restrict__ dbc_b, const float* __restrict__ Ab,
    float* __restrict__ aprod, float* __restrict__ hloc)
{
    const int dir = blockIdx.z >> 4, c = blockIdx.z & 15;
    const ushortT* xcv = dir ? xcv_b : xcv_f;
    const ushortT* dt  = dir ? dt_b  : dt_f;
    const float* dbc   = dir ? dbc_b : dbc_f;
    const float* Alog  = dir ? Ab    : Af;
    const int g = threadIdx.x >> 4, s = threadIdx.x & 15;
    const int d = blockIdx.x * 16 + g, b = blockIdx.y;

    const float A = -__expf(Alog[d * S_ + s]);
    float h = 0.f, sdt = 0.f;
    for (int j = 0; j < CL_; ++j) {
        int tau = c * CL_ + j;
        int pos = dir ? (L_ - 1 - tau) : tau;
        size_t row = (size_t)b * L_ + pos;
        float dtv = bf2f(dt[row * DI_ + d]);
        float xv  = bf2f(xcv[row * DI_ + d]);
        float Bv  = dbc[row * 80 + R_ + s];
        float a = __expf(dtv * A);
        h = a * h + dtv * Bv * xv;
        sdt += dtv;
    }
    int idx = (((dir * B_ + b) * NC_ + c) * DI_ + d) * S_ + s;
    aprod[idx] = __expf(A * sdt);
    hloc[idx] = h;
}

// ---------------------------------------------------------------------------
// Scan pass 2: prefix over chunks -> hin
// ---------------------------------------------------------------------------
__global__ __launch_bounds__(256) void scan2_k(
    const float* __restrict__ aprod, const float* __restrict__ hloc,
    float* __restrict__ hin)
{
    int q = blockIdx.x * 256 + threadIdx.x;
    if (q >= 2 * B_ * DI_ * S_) return;
    int s = q & 15;
    int t = q >> 4;
    int d = t % DI_;
    int t2 = t / DI_;
    int b = t2 & 1, dir = t2 >> 1;
    float h = 0.f;
    for (int c = 0; c < NC_; ++c) {
        int idx = (((dir * B_ + b) * NC_ + c) * DI_ + d) * S_ + s;
        hin[idx] = h;
        h = hloc[idx] + aprod[idx] * h;
    }
}

// ---------------------------------------------------------------------------
// Scan pass 3: re-run chunk with h_in, emit y' = (y + xv*Dp)*silu(z) as bf16
// written IN-PLACE over the z half of xz (same element, read-then-write).
// ---------------------------------------------------------------------------
__global__ __launch_bounds__(256) void scan3_k(
    const ushortT* __restrict__ xcv_f, const ushortT* __restrict__ dt_f,
    const float* __restrict__ dbc_f, const float* __restrict__ Af,
    const float* __restrict__ Dp_f, ushortT* __restrict__ xz_f,
    const ushortT* __restrict__ xcv_b, const ushortT* __restrict__ dt_b,
    const float* __restrict__ dbc_b, const float* __restrict__ Ab,
    const float* __restrict__ Dp_b, ushortT* __restrict__ xz_b,
    const float* __restrict__ hin)
{
    const int dir = blockIdx.z >> 4, c = blockIdx.z & 15;
    const ushortT* xcv = dir ? xcv_b : xcv_f;
    const ushortT* dt  = dir ? dt_b  : dt_f;
    const float* dbc   = dir ? dbc_b : dbc_f;
    const float* Alog  = dir ? Ab    : Af;
    const float* Dp    = dir ? Dp_b  : Dp_f;
    ushortT* xz        = dir ? xz_b  : xz_f;
    const int g = threadIdx.x >> 4, s = threadIdx.x & 15;
    const int d = blockIdx.x * 16 + g, b = blockIdx.y;

    const float A = -__expf(Alog[d * S_ + s]);
    const float Dpv = Dp[d];
    int idx = (((dir * B_ + b) * NC_ + c) * DI_ + d) * S_ + s;
    float h = hin[idx];

    for (int j = 0; j < CL_; ++j) {
        int tau = c * CL_ + j;
        int pos = dir ? (L_ - 1 - tau) : tau;
        size_t row = (size_t)b * L_ + pos;
        float dtv = bf2f(dt[row * DI_ + d]);
        float xv  = bf2f(xcv[row * DI_ + d]);
        float Bv  = dbc[row * 80 + R_ + s];
        float Cv  = dbc[row * 80 + R_ + S_ + s];
        h = __expf(dtv * A) * h + dtv * Bv * xv;
        float p = h * Cv;
        p += __shfl_xor(p, 8);
        p += __shfl_xor(p, 4);
        p += __shfl_xor(p, 2);
        p += __shfl_xor(p, 1);
        if (s == 0) {
            size_t zi = row * 3072 + DI_ + d;
            float zv = bf2f(xz[zi]);
            xz[zi] = f2bf((p + xv * Dpv) * siluf(zv));
        }
    }
}

// ---------------------------------------------------------------------------
// h = x + acc + proj_b ; LayerNorm over D=768
// ---------------------------------------------------------------------------
__global__ __launch_bounds__(256) void final_ln_k(
    const float* __restrict__ x, const float* __restrict__ acc,
    const float* __restrict__ proj_b, const float* __restrict__ ln_g,
    const float* __restrict__ ln_b, float* __restrict__ out)
{
    const int row = blockIdx.x;
    const size_t base = (size_t)row * D_;
    __shared__ float hbuf[D_];
    __shared__ float wsum[4], wsum2[4];
    float s1 = 0.f, s2 = 0.f;
    for (int n = threadIdx.x; n < D_; n += 256) {
        float h = x[base + n] + acc[base + n] + proj_b[n];
        hbuf[n] = h;
        s1 += h; s2 += h * h;
    }
    #pragma unroll
    for (int off = 32; off; off >>= 1) {
        s1 += __shfl_down(s1, off);
        s2 += __shfl_down(s2, off);
    }
    const int wid = threadIdx.x >> 6;
    if ((threadIdx.x & 63) == 0) { wsum[wid] = s1; wsum2[wid] = s2; }
    __syncthreads();
    if (threadIdx.x == 0) {
        float t1 = wsum[0] + wsum[1] + wsum[2] + wsum[3];
        float t2 = wsum2[0] + wsum2[1] + wsum2[2] + wsum2[3];
        float mu = t1 / D_;
        wsum[0] = mu;
        wsum2[0] = t2 / D_ - mu * mu;
    }
    __syncthreads();
    const float mu = wsum[0];
    const float inv = rsqrtf(wsum2[0] + 1e-5f);
    for (int n = threadIdx.x; n < D_; n += 256) {
        out[base + n] = (hbuf[n] - mu) * inv * ln_g[n] + ln_b[n];
    }
}

// ---------------------------------------------------------------------------
extern "C" void kernel_launch(void* const* d_in, const int* in_sizes, int n_in,
                              void* d_out, int out_size, void* d_ws, size_t ws_size,
                              hipStream_t stream)
{
    const float* x        = (const float*)d_in[0];
    const float* f_in_w   = (const float*)d_in[1];
    const float* f_conv_w = (const float*)d_in[2];
    const float* f_conv_b = (const float*)d_in[3];
    const float* f_xproj  = (const float*)d_in[4];
    const float* f_dt_w   = (const float*)d_in[5];
    const float* f_dt_bv  = (const float*)d_in[6];
    const float* f_A_log  = (const float*)d_in[7];
    const float* f_Dp     = (const float*)d_in[8];
    const float* f_out_w  = (const float*)d_in[9];
    const float* b_in_w   = (const float*)d_in[10];
    const float* b_conv_w = (const float*)d_in[11];
    const float* b_conv_b = (const float*)d_in[12];
    const float* b_xproj  = (const float*)d_in[13];
    const float* b_dt_w   = (const float*)d_in[14];
    const float* b_dt_bv  = (const float*)d_in[15];
    const float* b_A_log  = (const float*)d_in[16];
    const float* b_Dp     = (const float*)d_in[17];
    const float* b_out_w  = (const float*)d_in[18];
    const float* proj_w   = (const float*)d_in[19];
    const float* proj_b   = (const float*)d_in[20];
    const float* ln_g     = (const float*)d_in[21];
    const float* ln_b     = (const float*)d_in[22];
    float* out = (float*)d_out;

    // ---- workspace layout (float units) ----
    float* p = (float*)d_ws;
    ushortT* xbf     = (ushortT*)p;  p += (size_t)M_ * D_ / 2;          // 4096x768 bf16
    ushortT* wbf     = (ushortT*)p;  p += (size_t)2 * DI_ * D_ / 2;     // 3072x768 bf16 (reused f,b)
    ushortT* xz_f    = (ushortT*)p;  p += (size_t)M_ * 3072 / 2;        // 4096x3072 bf16
    ushortT* xz_b    = (ushortT*)p;  p += (size_t)M_ * 3072 / 2;
    ushortT* xcv_f   = (ushortT*)p;  p += (size_t)M_ * DI_ / 2;         // 4096x1536 bf16
    ushortT* xcv_b   = (ushortT*)p;  p += (size_t)M_ * DI_ / 2;
    ushortT* dtb_f   = (ushortT*)p;  p += (size_t)M_ * DI_ / 2;         // aliased -> merged
    ushortT* dtb_b   = (ushortT*)p;  p += (size_t)M_ * DI_ / 2;         // aliased -> accb
    float*   dbc_f   = p;            p += (size_t)M_ * 80;
    float*   dbc_b   = p;            p += (size_t)M_ * 80;
    ushortT* xprojbf = (ushortT*)p;  p += (size_t)128 * DI_ / 2;        // padded 128 rows
    ushortT* outwbf  = (ushortT*)p;  p += (size_t)D_ * DI_ / 2;         // reused f,b
    ushortT* projwbf = (ushortT*)p;  p += (size_t)D_ * DI_ / 2;
    float*   aprod   = p;            p += (size_t)2 * B_ * NC_ * DI_ * S_;
    float*   hloc    = p;            p += (size_t)2 * B_ * NC_ * DI_ * S_;
    float*   hin     = p;            p += (size_t)2 * B_ * NC_ * DI_ * S_;
    // aliases over dead dt buffers:
    ushortT* merged  = dtb_f;        // 4096x1536 bf16
    float*   accb    = (float*)dtb_b;// 4096x768 fp32 (same byte size)
    // yp lives in-place over the z half of xz_{f,b} (stride 3072, offset 1536)

    dim3 blk(256);

    // ---- convert static operands ----
    f2bf_k<<<2048, blk, 0, stream>>>(x, xbf, M_ * D_, M_ * D_);
    f2bf_k<<<1024, blk, 0, stream>>>(proj_w, projwbf, D_ * DI_, D_ * DI_);

    // ---- 1) xz = x @ in_w^T (both halves), bf16 out ----
    f2bf_k<<<2048, blk, 0, stream>>>(f_in_w, wbf, 2 * DI_ * D_, 2 * DI_ * D_);
    mfma_nt<ushortT, false><<<dim3(24, 32), blk, 0, stream>>>(
        xbf, D_, wbf, D_, xz_f, 3072, M_, D_, 3072);
    f2bf_k<<<2048, blk, 0, stream>>>(b_in_w, wbf, 2 * DI_ * D_, 2 * DI_ * D_);
    mfma_nt<ushortT, false><<<dim3(24, 32), blk, 0, stream>>>(
        xbf, D_, wbf, D_, xz_b, 3072, M_, D_, 3072);

    // ---- 2) depthwise conv + SiLU ----
    int cb = (B_ * L_ * DI_ + 255) / 256;
    conv_silu_k<<<cb, blk, 0, stream>>>(xz_f, f_conv_w, f_conv_b, xcv_f, 0);
    conv_silu_k<<<cb, blk, 0, stream>>>(xz_b, b_conv_w, b_conv_b, xcv_b, 1);

    // ---- 3) dbc = xcv @ xproj^T (N=80 padded to 128), fp32 out ----
    f2bf_k<<<512, blk, 0, stream>>>(f_xproj, xprojbf, 80 * DI_, 128 * DI_);
    mfma_nt<float, true><<<dim3(1, 32), blk, 0, stream>>>(
        xcv_f, DI_, xprojbf, DI_, dbc_f, 80, M_, DI_, 80);
    f2bf_k<<<512, blk, 0, stream>>>(b_xproj, xprojbf, 80 * DI_, 128 * DI_);
    mfma_nt<float, true><<<dim3(1, 32), blk, 0, stream>>>(
        xcv_b, DI_, xprojbf, DI_, dbc_b, 80, M_, DI_, 80);

    // ---- 4) dt = softplus(dbc[:,:48] @ dt_w^T + dt_b), bf16 out ----
    gemm_dt<<<dim3(24, 64), blk, 0, stream>>>(dbc_f, 80, f_dt_w, R_, dtb_f, DI_, f_dt_bv, M_, DI_, R_);
    gemm_dt<<<dim3(24, 64), blk, 0, stream>>>(dbc_b, 80, b_dt_w, R_, dtb_b, DI_, b_dt_bv, M_, DI_, R_);

    // ---- 5) chunked selective scan ----
    scan1_k<<<dim3(DI_ / 16, B_, 2 * NC_), blk, 0, stream>>>(
        xcv_f, dtb_f, dbc_f, f_A_log, xcv_b, dtb_b, dbc_b, b_A_log, aprod, hloc);
    scan2_k<<<(2 * B_ * DI_ * S_ + 255) / 256, blk, 0, stream>>>(aprod, hloc, hin);
    scan3_k<<<dim3(DI_ / 16, B_, 2 * NC_), blk, 0, stream>>>(
        xcv_f, dtb_f, dbc_f, f_A_log, f_Dp, xz_f,
        xcv_b, dtb_b, dbc_b, b_A_log, b_Dp, xz_b, hin);

    // ---- 6) merged = [yp_f @ f_out_w^T | yp_b @ b_out_w^T], bf16 ----
    f2bf_k<<<1024, blk, 0, stream>>>(f_out_w, outwbf, D_ * DI_, D_ * DI_);
    mfma_nt<ushortT, false><<<dim3(6, 32), blk, 0, stream>>>(
        xz_f + DI_, 3072, outwbf, DI_, merged, DI_, M_, DI_, D_);
    f2bf_k<<<1024, blk, 0, stream>>>(b_out_w, outwbf, D_ * DI_, D_ * DI_);
    mfma_nt<ushortT, false><<<dim3(6, 32), blk, 0, stream>>>(
        xz_b + DI_, 3072, outwbf, DI_, merged + D_, DI_, M_, DI_, D_);

    // ---- 7) accb = merged @ proj_w^T, fp32 ----
    mfma_nt<float, false><<<dim3(6, 32), blk, 0, stream>>>(
        merged, DI_, projwbf, DI_, accb, D_, M_, DI_, D_);

    // ---- 8) residual + LayerNorm ----
    final_ln_k<<<M_, blk, 0, stream>>>(x, accb, proj_b, ln_g, ln_b, out);
}

// Round 3
// 666.659 us; speedup vs baseline: 6.6234x; 1.3044x over previous
//
#include <hip/hip_runtime.h>
#include <math.h>

#define B_   2
#define L_   2048
#define D_   768
#define DI_  1536
#define S_   16
#define R_   48
#define M_   (B_*L_)   // 4096 tokens
#define NC_  32        // scan chunks
#define CL_  64        // chunk length

typedef unsigned short ushortT;
typedef __attribute__((ext_vector_type(4))) float f32x4;
typedef __attribute__((ext_vector_type(8))) short short8;

#if __has_builtin(__builtin_amdgcn_exp2f)
#define EXP2F(x) __builtin_amdgcn_exp2f(x)
#define KSC_ 1.4426950408889634f
#else
#define EXP2F(x) __expf(x)
#define KSC_ 1.0f
#endif

__device__ __forceinline__ float siluf(float x) { return x / (1.f + __expf(-x)); }

__device__ __forceinline__ ushortT f2bf(float f) {
    unsigned u = __float_as_uint(f);
    unsigned r = (u + 0x7FFFu + ((u >> 16) & 1u)) >> 16;
    return (ushortT)r;
}
__device__ __forceinline__ float bf2f(ushortT h) {
    return __uint_as_float(((unsigned)h) << 16);
}

__device__ __forceinline__ void stage16(const ushortT* g, ushortT* l) {
    __builtin_amdgcn_global_load_lds(
        (const __attribute__((address_space(1))) unsigned int*)g,
        (__attribute__((address_space(3))) unsigned int*)l, 16, 0, 0);
}

__device__ __forceinline__ void storeC(float* p, float v)   { *p = v; }
__device__ __forceinline__ void storeC(ushortT* p, float v) { *p = f2bf(v); }

// ---------------------------------------------------------------------------
// fp32 -> bf16 convert with optional zero-pad to ntot
// ---------------------------------------------------------------------------
__global__ __launch_bounds__(256) void f2bf_k(
    const float* __restrict__ in, ushortT* __restrict__ out, int n, int ntot)
{
    for (int i = blockIdx.x * 256 + threadIdx.x; i < ntot; i += gridDim.x * 256)
        out[i] = (i < n) ? f2bf(in[i]) : (ushortT)0;
}

// ---------------------------------------------------------------------------
// fp32 [rows][instride] (first usecols cols) -> bf16 [rows][outcols] zero-pad
// ---------------------------------------------------------------------------
__global__ __launch_bounds__(256) void pack_pad_k(
    const float* __restrict__ in, ushortT* __restrict__ out,
    int instride, int usecols, int outcols, long total)
{
    for (long i = (long)blockIdx.x * 256 + threadIdx.x; i < total; i += (long)gridDim.x * 256) {
        int c = (int)(i % outcols);
        long r = i / outcols;
        out[i] = (c < usecols) ? f2bf(in[r * instride + c]) : (ushortT)0;
    }
}

// ---------------------------------------------------------------------------
// bf16 transpose: in [B][L][DI] -> out [B][DI][L]; REV flips t on output
// ---------------------------------------------------------------------------
template<int REV>
__global__ __launch_bounds__(256) void transpose_k(
    const ushortT* __restrict__ in, ushortT* __restrict__ out)
{
    __shared__ ushortT tile[64][68];
    const int t0 = blockIdx.x * 64;
    const int d0 = blockIdx.y * 64;
    const int b  = blockIdx.z;
    const int tid = threadIdx.x;
    #pragma unroll 4
    for (int it = 0; it < 16; ++it) {
        int tt = it * 4 + (tid >> 6);
        int dd = tid & 63;
        tile[tt][dd] = in[((size_t)b * L_ + t0 + tt) * DI_ + d0 + dd];
    }
    __syncthreads();
    #pragma unroll 4
    for (int it = 0; it < 16; ++it) {
        int dd = it * 4 + (tid >> 6);
        int tt = tid & 63;
        int tw = REV ? (L_ - 1 - (t0 + tt)) : (t0 + tt);
        out[((size_t)b * DI_ + d0 + dd) * L_ + tw] = tile[tt][dd];
    }
}

// ---------------------------------------------------------------------------
// MFMA GEMM: C[M][ldc] = A[M][lda](bf16) @ W[Npad][ldw](bf16)^T
// 128x128 tile, BK=32, 4 waves (2x2), global_load_lds staging.
// EPI 0: plain ; EPI 1: softplus(acc + bias[col])
// ---------------------------------------------------------------------------
template<typename OutT, bool NMASK, int EPI>
__global__ __launch_bounds__(256) void mfma_nt(
    const ushortT* __restrict__ A, int lda,
    const ushortT* __restrict__ W, int ldw,
    OutT* __restrict__ C, int ldc,
    const float* __restrict__ bias,
    int M, int K, int Nreal)
{
    __shared__ ushortT As[128 * 32];
    __shared__ ushortT Ws[128 * 32];
    const int tid = threadIdx.x;
    const int lane = tid & 63, wid = tid >> 6;
    const int wr = wid >> 1, wc = wid & 1;
    const int m0 = blockIdx.y * 128, n0 = blockIdx.x * 128;

    f32x4 acc[4][4];
    #pragma unroll
    for (int m = 0; m < 4; ++m)
        #pragma unroll
        for (int n = 0; n < 4; ++n)
            acc[m][n] = (f32x4){0.f, 0.f, 0.f, 0.f};

    const int kq = (lane >> 4) * 8;
    const int lr = lane & 15;

    for (int k0 = 0; k0 < K; k0 += 32) {
        #pragma unroll
        for (int r = 0; r < 2; ++r) {
            int off = r * 4096 + tid * 16;
            int row = off >> 6;
            int col = (off & 63) >> 1;
            int lbase = r * 2048 + wid * 512;
            stage16(A + (size_t)(m0 + row) * lda + k0 + col, As + lbase);
            stage16(W + (size_t)(n0 + row) * ldw + k0 + col, Ws + lbase);
        }
        __syncthreads();

        short8 afr[4], bfr[4];
        #pragma unroll
        for (int m = 0; m < 4; ++m)
            afr[m] = *(const short8*)(As + (wr * 64 + m * 16 + lr) * 32 + kq);
        #pragma unroll
        for (int n = 0; n < 4; ++n)
            bfr[n] = *(const short8*)(Ws + (wc * 64 + n * 16 + lr) * 32 + kq);
        #pragma unroll
        for (int m = 0; m < 4; ++m)
            #pragma unroll
            for (int n = 0; n < 4; ++n)
                acc[m][n] = __builtin_amdgcn_mfma_f32_16x16x32_bf16(
                    afr[m], bfr[n], acc[m][n], 0, 0, 0);
        __syncthreads();
    }

    #pragma unroll
    for (int m = 0; m < 4; ++m) {
        #pragma unroll
        for (int n = 0; n < 4; ++n) {
            int colg = n0 + wc * 64 + n * 16 + (lane & 15);
            if (NMASK && colg >= Nreal) continue;
            #pragma unroll
            for (int r = 0; r < 4; ++r) {
                int rowg = m0 + wr * 64 + m * 16 + (lane >> 4) * 4 + r;
                float v = acc[m][n][r];
                if (EPI == 1) {
                    v += bias[colg];
                    v = (v > 20.f) ? v : log1pf(__expf(v));
                }
                storeC(&C[(size_t)rowg * ldc + colg], v);
            }
        }
    }
}

// ---------------------------------------------------------------------------
// Depthwise conv (K=4) + bias + SiLU. Reads xc [M][DI] bf16, writes xcv bf16.
// ---------------------------------------------------------------------------
__global__ __launch_bounds__(256) void conv_silu_k(
    const ushortT* __restrict__ xc, const float* __restrict__ cw,
    const float* __restrict__ cb, ushortT* __restrict__ out, int rev)
{
    int idx = blockIdx.x * 256 + threadIdx.x;
    if (idx >= B_ * L_ * DI_) return;
    int d = idx % DI_;
    int l = (idx / DI_) % L_;
    int b = idx / (DI_ * L_);
    float acc = cb[d];
    #pragma unroll
    for (int j = 0; j < 4; ++j) {
        int ll = rev ? (l + 3 - j) : (l + j - 3);
        if (ll >= 0 && ll < L_)
            acc += cw[d * 4 + j] * bf2f(xc[((size_t)b * L_ + ll) * DI_ + d]);
    }
    out[idx] = f2bf(siluf(acc));
}

// ---------------------------------------------------------------------------
// Scan pass 1: thread-per-channel, 16 states in registers.
// grid (DI/256, B, 2*NC); writes aprod, hloc.
// ---------------------------------------------------------------------------
__global__ __launch_bounds__(256) void scan1_k(
    const ushortT* __restrict__ xcv_t_f, const ushortT* __restrict__ dt_t_f,
    const float* __restrict__ dbc_f, const float* __restrict__ Af,
    const ushortT* __restrict__ xcv_t_b, const ushortT* __restrict__ dt_t_b,
    const float* __restrict__ dbc_b, const float* __restrict__ Ab,
    float* __restrict__ aprod, float* __restrict__ hloc)
{
    const int dir = blockIdx.z / NC_, c = blockIdx.z % NC_;
    const ushortT* xcv_t = dir ? xcv_t_b : xcv_t_f;
    const ushortT* dt_t  = dir ? dt_t_b  : dt_t_f;
    const float* dbc = dir ? dbc_b : dbc_f;
    const float* Alog = dir ? Ab : Af;
    const int tid = threadIdx.x;
    const int d = blockIdx.x * 256 + tid;
    const int b = blockIdx.y;
    const int t0 = c * CL_;

    __shared__ float Bs[CL_][16];
    #pragma unroll
    for (int it = 0; it < CL_ / 16; ++it) {
        int row = it * 16 + (tid >> 4);
        int col = tid & 15;
        int tau = t0 + row;
        int pos = dir ? (L_ - 1 - tau) : tau;
        Bs[row][col] = dbc[((size_t)b * L_ + pos) * 80 + R_ + col];
    }
    __syncthreads();

    float A2[16];
    #pragma unroll
    for (int s = 0; s < 16; ++s)
        A2[s] = -__expf(Alog[d * S_ + s]) * KSC_;

    const ushortT* dtp = dt_t  + ((size_t)b * DI_ + d) * L_ + t0;
    const ushortT* xvp = xcv_t + ((size_t)b * DI_ + d) * L_ + t0;

    float h[16];
    #pragma unroll
    for (int s = 0; s < 16; ++s) h[s] = 0.f;
    float sdt = 0.f;

    for (int u = 0; u < CL_ / 8; ++u) {
        short8 dt8 = *(const short8*)(dtp + u * 8);
        short8 xv8 = *(const short8*)(xvp + u * 8);
        #pragma unroll
        for (int e = 0; e < 8; ++e) {
            float dtv = bf2f((ushortT)dt8[e]);
            float xv  = bf2f((ushortT)xv8[e]);
            float bx = dtv * xv;
            int j = u * 8 + e;
            float Bv[16];
            const f32x4* B4 = (const f32x4*)&Bs[j][0];
            *(f32x4*)&Bv[0]  = B4[0];
            *(f32x4*)&Bv[4]  = B4[1];
            *(f32x4*)&Bv[8]  = B4[2];
            *(f32x4*)&Bv[12] = B4[3];
            sdt += dtv;
            #pragma unroll
            for (int s = 0; s < 16; ++s) {
                float a = EXP2F(dtv * A2[s]);
                h[s] = a * h[s] + bx * Bv[s];
            }
        }
    }
    size_t idx = ((((size_t)dir * B_ + b) * NC_ + c) * DI_ + d) * S_;
    #pragma unroll
    for (int q = 0; q < 4; ++q) {
        f32x4 ap, hl;
        #pragma unroll
        for (int e = 0; e < 4; ++e) {
            ap[e] = EXP2F(A2[q * 4 + e] * sdt);
            hl[e] = h[q * 4 + e];
        }
        *(f32x4*)(aprod + idx + q * 4) = ap;
        *(f32x4*)(hloc  + idx + q * 4) = hl;
    }
}

// ---------------------------------------------------------------------------
// Scan pass 2: prefix over chunks; hin written IN-PLACE over aprod.
// ---------------------------------------------------------------------------
__global__ __launch_bounds__(256) void scan2_k(
    float* __restrict__ aprod, const float* __restrict__ hloc)
{
    int q = blockIdx.x * 256 + threadIdx.x;
    if (q >= 2 * B_ * DI_ * S_) return;
    int s = q & 15;
    int t = q >> 4;
    int d = t % DI_;
    int t2 = t / DI_;
    int b = t2 & 1, dir = t2 >> 1;
    float h = 0.f;
    for (int c = 0; c < NC_; ++c) {
        size_t idx = ((((size_t)dir * B_ + b) * NC_ + c) * DI_ + d) * S_ + s;
        float a = aprod[idx], hl = hloc[idx];
        aprod[idx] = h;          // h_in for chunk c
        h = hl + a * h;
    }
}

// ---------------------------------------------------------------------------
// Scan pass 3: recompute with h_in, emit raw y = sum_s h*C to y_t [B][DI][L] bf16.
// ---------------------------------------------------------------------------
__global__ __launch_bounds__(256) void scan3_k(
    const ushortT* __restrict__ xcv_t_f, const ushortT* __restrict__ dt_t_f,
    const float* __restrict__ dbc_f, const float* __restrict__ Af, ushortT* __restrict__ y_t_f,
    const ushortT* __restrict__ xcv_t_b, const ushortT* __restrict__ dt_t_b,
    const float* __restrict__ dbc_b, const float* __restrict__ Ab, ushortT* __restrict__ y_t_b,
    const float* __restrict__ hin)
{
    const int dir = blockIdx.z / NC_, c = blockIdx.z % NC_;
    const ushortT* xcv_t = dir ? xcv_t_b : xcv_t_f;
    const ushortT* dt_t  = dir ? dt_t_b  : dt_t_f;
    const float* dbc = dir ? dbc_b : dbc_f;
    const float* Alog = dir ? Ab : Af;
    ushortT* y_t = dir ? y_t_b : y_t_f;
    const int tid = threadIdx.x;
    const int d = blockIdx.x * 256 + tid;
    const int b = blockIdx.y;
    const int t0 = c * CL_;

    __shared__ float Bs[CL_][16];
    __shared__ float Cs[CL_][16];
    #pragma unroll
    for (int it = 0; it < CL_ / 16; ++it) {
        int row = it * 16 + (tid >> 4);
        int col = tid & 15;
        int tau = t0 + row;
        int pos = dir ? (L_ - 1 - tau) : tau;
        size_t base = ((size_t)b * L_ + pos) * 80 + R_;
        Bs[row][col] = dbc[base + col];
        Cs[row][col] = dbc[base + 16 + col];
    }
    __syncthreads();

    float A2[16];
    #pragma unroll
    for (int s = 0; s < 16; ++s)
        A2[s] = -__expf(Alog[d * S_ + s]) * KSC_;

    size_t idx = ((((size_t)dir * B_ + b) * NC_ + c) * DI_ + d) * S_;
    float h[16];
    #pragma unroll
    for (int q = 0; q < 4; ++q) {
        f32x4 hv = *(const f32x4*)(hin + idx + q * 4);
        h[q * 4 + 0] = hv[0]; h[q * 4 + 1] = hv[1];
        h[q * 4 + 2] = hv[2]; h[q * 4 + 3] = hv[3];
    }

    const ushortT* dtp = dt_t  + ((size_t)b * DI_ + d) * L_ + t0;
    const ushortT* xvp = xcv_t + ((size_t)b * DI_ + d) * L_ + t0;
    ushortT* ytp = y_t + ((size_t)b * DI_ + d) * L_ + t0;

    union { ushortT u[4]; unsigned long long v; } pk;

    for (int u = 0; u < CL_ / 8; ++u) {
        short8 dt8 = *(const short8*)(dtp + u * 8);
        short8 xv8 = *(const short8*)(xvp + u * 8);
        #pragma unroll
        for (int e = 0; e < 8; ++e) {
            float dtv = bf2f((ushortT)dt8[e]);
            float xv  = bf2f((ushortT)xv8[e]);
            float bx = dtv * xv;
            int j = u * 8 + e;
            float Bv[16], Cv[16];
            const f32x4* B4 = (const f32x4*)&Bs[j][0];
            const f32x4* C4 = (const f32x4*)&Cs[j][0];
            *(f32x4*)&Bv[0]  = B4[0]; *(f32x4*)&Bv[4]  = B4[1];
            *(f32x4*)&Bv[8]  = B4[2]; *(f32x4*)&Bv[12] = B4[3];
            *(f32x4*)&Cv[0]  = C4[0]; *(f32x4*)&Cv[4]  = C4[1];
            *(f32x4*)&Cv[8]  = C4[2]; *(f32x4*)&Cv[12] = C4[3];
            float y = 0.f;
            #pragma unroll
            for (int s = 0; s < 16; ++s) {
                float a = EXP2F(dtv * A2[s]);
                h[s] = a * h[s] + bx * Bv[s];
                y += h[s] * Cv[s];
            }
            pk.u[j & 3] = f2bf(y);
            if ((j & 3) == 3)
                *(unsigned long long*)(ytp + (j - 3)) = pk.v;
        }
    }
}

// ---------------------------------------------------------------------------
// Gate: yp[m][d] = (y + xv*Dp[d]) * silu(z), y LDS-transposed from y_t.
// Writes in place over xcv. grid (M/64, DI/64, 2)
// ---------------------------------------------------------------------------
__global__ __launch_bounds__(256) void gate_k(
    const ushortT* __restrict__ y_t_f, const ushortT* __restrict__ y_t_b,
    ushortT* __restrict__ xcv_f, ushortT* __restrict__ xcv_b,
    const ushortT* __restrict__ z_f, const ushortT* __restrict__ z_b,
    const float* __restrict__ Dp_f, const float* __restrict__ Dp_b)
{
    const int dir = blockIdx.z;
    const ushortT* y_t = dir ? y_t_b : y_t_f;
    ushortT* xcv = dir ? xcv_b : xcv_f;
    const ushortT* z = dir ? z_b : z_f;
    const float* Dp = dir ? Dp_b : Dp_f;
    const int tid = threadIdx.x;
    const int m0 = blockIdx.x * 64;
    const int d0 = blockIdx.y * 64;
    const int b = m0 / L_;
    const int t0 = m0 % L_;
    __shared__ ushortT ys[64][68];
    #pragma unroll 4
    for (int it = 0; it < 16; ++it) {
        int r = it * 4 + (tid >> 6);
        int cc = tid & 63;
        int tt = dir ? (L_ - 1 - (t0 + cc)) : (t0 + cc);
        ys[r][cc] = y_t[((size_t)b * DI_ + d0 + r) * L_ + tt];
    }
    __syncthreads();
    const int dd = tid & 63;
    const float Dpv = Dp[d0 + dd];
    #pragma unroll 4
    for (int it = 0; it < 16; ++it) {
        int mi = it * 4 + (tid >> 6);
        size_t m = (size_t)m0 + mi;
        size_t xi = m * DI_ + d0 + dd;
        float yv = bf2f(ys[dd][mi]);
        float xv = bf2f(xcv[xi]);
        float zv = bf2f(z[xi]);
        xcv[xi] = f2bf((yv + xv * Dpv) * siluf(zv));
    }
}

// ---------------------------------------------------------------------------
// h = x + acc + proj_b ; LayerNorm over D=768
// ---------------------------------------------------------------------------
__global__ __launch_bounds__(256) void final_ln_k(
    const float* __restrict__ x, const float* __restrict__ acc,
    const float* __restrict__ proj_b, const float* __restrict__ ln_g,
    const float* __restrict__ ln_b, float* __restrict__ out)
{
    const int row = blockIdx.x;
    const size_t base = (size_t)row * D_;
    __shared__ float hbuf[D_];
    __shared__ float wsum[4], wsum2[4];
    float s1 = 0.f, s2 = 0.f;
    for (int n = threadIdx.x; n < D_; n += 256) {
        float h = x[base + n] + acc[base + n] + proj_b[n];
        hbuf[n] = h;
        s1 += h; s2 += h * h;
    }
    #pragma unroll
    for (int off = 32; off; off >>= 1) {
        s1 += __shfl_down(s1, off);
        s2 += __shfl_down(s2, off);
    }
    const int wid = threadIdx.x >> 6;
    if ((threadIdx.x & 63) == 0) { wsum[wid] = s1; wsum2[wid] = s2; }
    __syncthreads();
    if (threadIdx.x == 0) {
        float t1 = wsum[0] + wsum[1] + wsum[2] + wsum[3];
        float t2 = wsum2[0] + wsum2[1] + wsum2[2] + wsum2[3];
        float mu = t1 / D_;
        wsum[0] = mu;
        wsum2[0] = t2 / D_ - mu * mu;
    }
    __syncthreads();
    const float mu = wsum[0];
    const float inv = rsqrtf(wsum2[0] + 1e-5f);
    for (int n = threadIdx.x; n < D_; n += 256) {
        out[base + n] = (hbuf[n] - mu) * inv * ln_g[n] + ln_b[n];
    }
}

// ---------------------------------------------------------------------------
extern "C" void kernel_launch(void* const* d_in, const int* in_sizes, int n_in,
                              void* d_out, int out_size, void* d_ws, size_t ws_size,
                              hipStream_t stream)
{
    const float* x        = (const float*)d_in[0];
    const float* f_in_w   = (const float*)d_in[1];
    const float* f_conv_w = (const float*)d_in[2];
    const float* f_conv_b = (const float*)d_in[3];
    const float* f_xproj  = (const float*)d_in[4];
    const float* f_dt_w   = (const float*)d_in[5];
    const float* f_dt_bv  = (const float*)d_in[6];
    const float* f_A_log  = (const float*)d_in[7];
    const float* f_Dp     = (const float*)d_in[8];
    const float* f_out_w  = (const float*)d_in[9];
    const float* b_in_w   = (const float*)d_in[10];
    const float* b_conv_w = (const float*)d_in[11];
    const float* b_conv_b = (const float*)d_in[12];
    const float* b_xproj  = (const float*)d_in[13];
    const float* b_dt_w   = (const float*)d_in[14];
    const float* b_dt_bv  = (const float*)d_in[15];
    const float* b_A_log  = (const float*)d_in[16];
    const float* b_Dp     = (const float*)d_in[17];
    const float* b_out_w  = (const float*)d_in[18];
    const float* proj_w   = (const float*)d_in[19];
    const float* proj_b   = (const float*)d_in[20];
    const float* ln_g     = (const float*)d_in[21];
    const float* ln_b     = (const float*)d_in[22];
    float* out = (float*)d_out;

    // ---- workspace layout (float units) ----
    const size_t TOKH = (size_t)M_ * DI_ / 2;   // bf16 [M][DI] in float units
    float* p = (float*)d_ws;
    ushortT* xbf     = (ushortT*)p;  p += (size_t)M_ * D_ / 2;
    ushortT* wbf     = (ushortT*)p;  p += (size_t)DI_ * D_ / 2;     // one in_w half at a time
    ushortT* xc_f    = (ushortT*)p;  p += TOKH;
    ushortT* z_f     = (ushortT*)p;  p += TOKH;
    ushortT* xc_b    = (ushortT*)p;  p += TOKH;
    ushortT* z_b     = (ushortT*)p;  p += TOKH;
    ushortT* xcv_f   = (ushortT*)p;  p += TOKH;
    ushortT* xcv_b   = (ushortT*)p;  p += TOKH;
    ushortT* xcvt_f  = (ushortT*)p;  p += TOKH;
    ushortT* xcvt_b  = (ushortT*)p;  p += TOKH;
    ushortT* dtbuf_f = (ushortT*)p;  p += TOKH;
    ushortT* dtbuf_b = (ushortT*)p;  p += TOKH;
    float*   dbc_f   = p;            p += (size_t)M_ * 80;
    float*   dbc_b   = p;            p += (size_t)M_ * 80;
    ushortT* dbc48bf = (ushortT*)p;  p += (size_t)M_ * 64 / 2;
    ushortT* dtwbf   = (ushortT*)p;  p += (size_t)DI_ * 64 / 2;
    ushortT* xprojbf = (ushortT*)p;  p += (size_t)128 * DI_ / 2;
    ushortT* outwbf  = (ushortT*)p;  p += (size_t)D_ * DI_ / 2;
    ushortT* projwbf = (ushortT*)p;  p += (size_t)D_ * DI_ / 2;
    float*   aprod   = p;            p += (size_t)2 * B_ * NC_ * DI_ * S_;
    float*   hloc    = p;            p += (size_t)2 * B_ * NC_ * DI_ * S_;
    // aliases (verified dead-before-reuse):
    ushortT* dtt_f   = xc_f;     // xc dead after conv
    ushortT* dtt_b   = xc_b;
    ushortT* ytt_f   = dtbuf_f;  // dt [t][d] dead after transpose
    ushortT* ytt_b   = dtbuf_b;
    ushortT* merged  = z_f;      // z dead after gate
    float*   accb    = (float*)z_b;

    dim3 blk(256);

    // ---- static converts ----
    f2bf_k<<<2048, blk, 0, stream>>>(x, xbf, M_ * D_, M_ * D_);
    f2bf_k<<<1024, blk, 0, stream>>>(proj_w, projwbf, D_ * DI_, D_ * DI_);

    // ---- 1) xc/z = x @ in_w^T halves ----
    f2bf_k<<<1024, blk, 0, stream>>>(f_in_w, wbf, DI_ * D_, DI_ * D_);
    mfma_nt<ushortT, false, 0><<<dim3(12, 32), blk, 0, stream>>>(
        xbf, D_, wbf, D_, xc_f, DI_, nullptr, M_, D_, DI_);
    f2bf_k<<<1024, blk, 0, stream>>>(f_in_w + (size_t)DI_ * D_, wbf, DI_ * D_, DI_ * D_);
    mfma_nt<ushortT, false, 0><<<dim3(12, 32), blk, 0, stream>>>(
        xbf, D_, wbf, D_, z_f, DI_, nullptr, M_, D_, DI_);
    f2bf_k<<<1024, blk, 0, stream>>>(b_in_w, wbf, DI_ * D_, DI_ * D_);
    mfma_nt<ushortT, false, 0><<<dim3(12, 32), blk, 0, stream>>>(
        xbf, D_, wbf, D_, xc_b, DI_, nullptr, M_, D_, DI_);
    f2bf_k<<<1024, blk, 0, stream>>>(b_in_w + (size_t)DI_ * D_, wbf, DI_ * D_, DI_ * D_);
    mfma_nt<ushortT, false, 0><<<dim3(12, 32), blk, 0, stream>>>(
        xbf, D_, wbf, D_, z_b, DI_, nullptr, M_, D_, DI_);

    // ---- 2) depthwise conv + SiLU ----
    int cb = (B_ * L_ * DI_ + 255) / 256;
    conv_silu_k<<<cb, blk, 0, stream>>>(xc_f, f_conv_w, f_conv_b, xcv_f, 0);
    conv_silu_k<<<cb, blk, 0, stream>>>(xc_b, b_conv_w, b_conv_b, xcv_b, 1);

    // ---- 3) transpose xcv -> [b][d][t] (bwd reversed) ----
    transpose_k<0><<<dim3(32, 24, 2), blk, 0, stream>>>(xcv_f, xcvt_f);
    transpose_k<1><<<dim3(32, 24, 2), blk, 0, stream>>>(xcv_b, xcvt_b);

    // ---- 4) dbc = xcv @ xproj^T (N=80 pad 128), fp32 ----
    f2bf_k<<<512, blk, 0, stream>>>(f_xproj, xprojbf, 80 * DI_, 128 * DI_);
    mfma_nt<float, true, 0><<<dim3(1, 32), blk, 0, stream>>>(
        xcv_f, DI_, xprojbf, DI_, dbc_f, 80, nullptr, M_, DI_, 80);
    f2bf_k<<<512, blk, 0, stream>>>(b_xproj, xprojbf, 80 * DI_, 128 * DI_);
    mfma_nt<float, true, 0><<<dim3(1, 32), blk, 0, stream>>>(
        xcv_b, DI_, xprojbf, DI_, dbc_b, 80, nullptr, M_, DI_, 80);

    // ---- 5) dt = softplus(dbc[:, :48] @ dt_w^T + dt_b) via MFMA (K pad 64) ----
    pack_pad_k<<<1024, blk, 0, stream>>>(dbc_f, dbc48bf, 80, 48, 64, (long)M_ * 64);
    pack_pad_k<<<384,  blk, 0, stream>>>(f_dt_w, dtwbf, 48, 48, 64, (long)DI_ * 64);
    mfma_nt<ushortT, false, 1><<<dim3(12, 32), blk, 0, stream>>>(
        dbc48bf, 64, dtwbf, 64, dtbuf_f, DI_, f_dt_bv, M_, 64, DI_);
    transpose_k<0><<<dim3(32, 24, 2), blk, 0, stream>>>(dtbuf_f, dtt_f);
    pack_pad_k<<<1024, blk, 0, stream>>>(dbc_b, dbc48bf, 80, 48, 64, (long)M_ * 64);
    pack_pad_k<<<384,  blk, 0, stream>>>(b_dt_w, dtwbf, 48, 48, 64, (long)DI_ * 64);
    mfma_nt<ushortT, false, 1><<<dim3(12, 32), blk, 0, stream>>>(
        dbc48bf, 64, dtwbf, 64, dtbuf_b, DI_, b_dt_bv, M_, 64, DI_);
    transpose_k<1><<<dim3(32, 24, 2), blk, 0, stream>>>(dtbuf_b, dtt_b);

    // ---- 6) chunked selective scan (thread-per-channel) ----
    scan1_k<<<dim3(DI_ / 256, B_, 2 * NC_), blk, 0, stream>>>(
        xcvt_f, dtt_f, dbc_f, f_A_log, xcvt_b, dtt_b, dbc_b, b_A_log, aprod, hloc);
    scan2_k<<<(2 * B_ * DI_ * S_ + 255) / 256, blk, 0, stream>>>(aprod, hloc);
    scan3_k<<<dim3(DI_ / 256, B_, 2 * NC_), blk, 0, stream>>>(
        xcvt_f, dtt_f, dbc_f, f_A_log, ytt_f,
        xcvt_b, dtt_b, dbc_b, b_A_log, ytt_b, aprod);

    // ---- 7) gate: yp = (y + xcv*Dp)*silu(z), in place over xcv ----
    gate_k<<<dim3(M_ / 64, DI_ / 64, 2), blk, 0, stream>>>(
        ytt_f, ytt_b, xcv_f, xcv_b, z_f, z_b, f_Dp, b_Dp);

    // ---- 8) merged = [yp_f @ f_out_w^T | yp_b @ b_out_w^T] ----
    f2bf_k<<<1024, blk, 0, stream>>>(f_out_w, outwbf, D_ * DI_, D_ * DI_);
    mfma_nt<ushortT, false, 0><<<dim3(6, 32), blk, 0, stream>>>(
        xcv_f, DI_, outwbf, DI_, merged, DI_, nullptr, M_, DI_, D_);
    f2bf_k<<<1024, blk, 0, stream>>>(b_out_w, outwbf, D_ * DI_, D_ * DI_);
    mfma_nt<ushortT, false, 0><<<dim3(6, 32), blk, 0, stream>>>(
        xcv_b, DI_, outwbf, DI_, merged + D_, DI_, nullptr, M_, DI_, D_);

    // ---- 9) accb = merged @ proj_w^T ----
    mfma_nt<float, false, 0><<<dim3(6, 32), blk, 0, stream>>>(
        merged, DI_, projwbf, DI_, accb, D_, nullptr, M_, DI_, D_);

    // ---- 10) residual + LayerNorm ----
    final_ln_k<<<M_, blk, 0, stream>>>(x, accb, proj_b, ln_g, ln_b, out);
}

// Round 4
// 402.891 us; speedup vs baseline: 10.9597x; 1.6547x over previous
//
#include <hip/hip_runtime.h>
#include <math.h>

#define B_   2
#define L_   2048
#define D_   768
#define DI_  1536
#define S_   16
#define R_   48
#define M_   (B_*L_)   // 4096 tokens
#define NC_  32        // scan chunks
#define CL_  64        // chunk length

typedef unsigned short ushortT;
typedef __attribute__((ext_vector_type(4))) float f32x4;
typedef __attribute__((ext_vector_type(8))) short short8;

#if __has_builtin(__builtin_amdgcn_exp2f)
#define EXP2F(x) __builtin_amdgcn_exp2f(x)
#define KSC_ 1.4426950408889634f
#else
#define EXP2F(x) __expf(x)
#define KSC_ 1.0f
#endif

__device__ __forceinline__ float siluf(float x) { return x / (1.f + __expf(-x)); }

__device__ __forceinline__ ushortT f2bf(float f) {
    unsigned u = __float_as_uint(f);
    unsigned r = (u + 0x7FFFu + ((u >> 16) & 1u)) >> 16;
    return (ushortT)r;
}
__device__ __forceinline__ float bf2f(ushortT h) {
    return __uint_as_float(((unsigned)h) << 16);
}

__device__ __forceinline__ void stage16(const ushortT* g, ushortT* l) {
    __builtin_amdgcn_global_load_lds(
        (const __attribute__((address_space(1))) unsigned int*)g,
        (__attribute__((address_space(3))) unsigned int*)l, 16, 0, 0);
}

__device__ __forceinline__ void storeC(float* p, float v)   { *p = v; }
__device__ __forceinline__ void storeC(ushortT* p, float v) { *p = f2bf(v); }

// ---------------------------------------------------------------------------
// Mega-convert: 8 segments fp32 -> bf16, with optional strided zero-pad.
// flat segment: use=out=1. padded: row-major [r][use] -> [r][out], pad 0.
// ---------------------------------------------------------------------------
struct Seg { const float* src; ushortT* dst; long n; int use; int out; };
struct Segs8 { Seg s[8]; };

__global__ __launch_bounds__(256) void convert_all_k(Segs8 S)
{
    const long stride = (long)gridDim.x * 256;
    for (int si = 0; si < 8; ++si) {
        Seg sg = S.s[si];
        if (sg.out == 1) {
            for (long i = blockIdx.x * 256L + threadIdx.x; i < sg.n; i += stride)
                sg.dst[i] = f2bf(sg.src[i]);
        } else {
            for (long i = blockIdx.x * 256L + threadIdx.x; i < sg.n; i += stride) {
                int c = (int)(i % sg.out);
                long r = i / sg.out;
                sg.dst[i] = (c < sg.use) ? f2bf(sg.src[r * sg.use + c]) : (ushortT)0;
            }
        }
    }
}

// ---------------------------------------------------------------------------
// dbc[:, :48] (stride 80 fp32) -> bf16 [M][64] zero-pad, both dirs
// ---------------------------------------------------------------------------
__global__ __launch_bounds__(256) void pack48_k(
    const float* __restrict__ a, const float* __restrict__ bsrc,
    ushortT* __restrict__ oa, ushortT* __restrict__ ob)
{
    const long n = (long)M_ * 64;
    for (long i = blockIdx.x * 256L + threadIdx.x; i < 2 * n; i += (long)gridDim.x * 256) {
        long j = (i >= n) ? i - n : i;
        const float* src = (i >= n) ? bsrc : a;
        ushortT* dst = (i >= n) ? ob : oa;
        int c = (int)(j & 63);
        long r = j >> 6;
        dst[j] = (c < 48) ? f2bf(src[r * 80 + c]) : (ushortT)0;
    }
}

// ---------------------------------------------------------------------------
// MFMA GEMM (bf16 A, bf16 W): C = A @ W^T, 128x128 tile, BK=32, 4 waves.
// z-slice selects pointer set. EPI 0: plain ; EPI 2: softplus(acc+bias[row])
// ---------------------------------------------------------------------------
struct P4 { const ushortT* A[4]; const ushortT* W[4]; void* C[4]; const float* bias[4]; };

template<typename OutT, bool NMASK, int EPI>
__global__ __launch_bounds__(256) void mfma_nt(
    P4 P, int lda, int ldw, int ldc, int M, int K, int Nreal)
{
    __shared__ ushortT As[128 * 32];
    __shared__ ushortT Ws[128 * 32];
    const ushortT* A = P.A[blockIdx.z];
    const ushortT* W = P.W[blockIdx.z];
    OutT* C = (OutT*)P.C[blockIdx.z];
    const float* bias = P.bias[blockIdx.z];
    const int tid = threadIdx.x;
    const int lane = tid & 63, wid = tid >> 6;
    const int wr = wid >> 1, wc = wid & 1;
    const int m0 = blockIdx.y * 128, n0 = blockIdx.x * 128;

    f32x4 acc[4][4];
    #pragma unroll
    for (int m = 0; m < 4; ++m)
        #pragma unroll
        for (int n = 0; n < 4; ++n)
            acc[m][n] = (f32x4){0.f, 0.f, 0.f, 0.f};

    const int kq = (lane >> 4) * 8;
    const int lr = lane & 15;

    for (int k0 = 0; k0 < K; k0 += 32) {
        #pragma unroll
        for (int r = 0; r < 2; ++r) {
            int off = r * 4096 + tid * 16;
            int row = off >> 6;
            int col = (off & 63) >> 1;
            int lbase = r * 2048 + wid * 512;
            stage16(A + (size_t)(m0 + row) * lda + k0 + col, As + lbase);
            stage16(W + (size_t)(n0 + row) * ldw + k0 + col, Ws + lbase);
        }
        __syncthreads();

        short8 afr[4], bfr[4];
        #pragma unroll
        for (int m = 0; m < 4; ++m)
            afr[m] = *(const short8*)(As + (wr * 64 + m * 16 + lr) * 32 + kq);
        #pragma unroll
        for (int n = 0; n < 4; ++n)
            bfr[n] = *(const short8*)(Ws + (wc * 64 + n * 16 + lr) * 32 + kq);
        #pragma unroll
        for (int m = 0; m < 4; ++m)
            #pragma unroll
            for (int n = 0; n < 4; ++n)
                acc[m][n] = __builtin_amdgcn_mfma_f32_16x16x32_bf16(
                    afr[m], bfr[n], acc[m][n], 0, 0, 0);
        __syncthreads();
    }

    #pragma unroll
    for (int m = 0; m < 4; ++m) {
        #pragma unroll
        for (int n = 0; n < 4; ++n) {
            int colg = n0 + wc * 64 + n * 16 + (lane & 15);
            if (NMASK && colg >= Nreal) continue;
            #pragma unroll
            for (int r = 0; r < 4; ++r) {
                int rowg = m0 + wr * 64 + m * 16 + (lane >> 4) * 4 + r;
                float v = acc[m][n][r];
                if (EPI == 2) {
                    v += bias[rowg];
                    v = (v > 20.f) ? v : log1pf(__expf(v));
                }
                storeC(&C[(size_t)rowg * ldc + colg], v);
            }
        }
    }
}

// ---------------------------------------------------------------------------
// MFMA GEMM with fp32 W source (converted during LDS staging). bf16 out.
// Used for xz = x @ in_w^T (z = 4 halves).
// ---------------------------------------------------------------------------
struct PW { const ushortT* A; const float* W[4]; ushortT* C[4]; };

__global__ __launch_bounds__(256) void mfma_wf(
    PW P, int lda, int ldw, int ldc, int M, int K)
{
    __shared__ ushortT As[128 * 32];
    __shared__ ushortT Ws[128 * 32];
    const ushortT* A = P.A;
    const float* W = P.W[blockIdx.z];
    ushortT* C = P.C[blockIdx.z];
    const int tid = threadIdx.x;
    const int lane = tid & 63, wid = tid >> 6;
    const int wr = wid >> 1, wc = wid & 1;
    const int m0 = blockIdx.y * 128, n0 = blockIdx.x * 128;

    f32x4 acc[4][4];
    #pragma unroll
    for (int m = 0; m < 4; ++m)
        #pragma unroll
        for (int n = 0; n < 4; ++n)
            acc[m][n] = (f32x4){0.f, 0.f, 0.f, 0.f};

    const int kq = (lane >> 4) * 8;
    const int lr = lane & 15;
    const int wrow = tid >> 1;            // W stage: row per 2 threads
    const int wch  = (tid & 1) * 16;      // 16-float half

    for (int k0 = 0; k0 < K; k0 += 32) {
        #pragma unroll
        for (int r = 0; r < 2; ++r) {
            int off = r * 4096 + tid * 16;
            int row = off >> 6;
            int col = (off & 63) >> 1;
            int lbase = r * 2048 + wid * 512;
            stage16(A + (size_t)(m0 + row) * lda + k0 + col, As + lbase);
        }
        {
            const float* ws = W + (size_t)(n0 + wrow) * ldw + k0 + wch;
            f32x4 f0 = *(const f32x4*)(ws + 0);
            f32x4 f1 = *(const f32x4*)(ws + 4);
            f32x4 f2 = *(const f32x4*)(ws + 8);
            f32x4 f3 = *(const f32x4*)(ws + 12);
            short8 p0, p1;
            #pragma unroll
            for (int e = 0; e < 4; ++e) {
                p0[e]     = (short)f2bf(f0[e]);
                p0[4 + e] = (short)f2bf(f1[e]);
                p1[e]     = (short)f2bf(f2[e]);
                p1[4 + e] = (short)f2bf(f3[e]);
            }
            *(short8*)(Ws + wrow * 32 + wch) = p0;
            *(short8*)(Ws + wrow * 32 + wch + 8) = p1;
        }
        __syncthreads();

        short8 afr[4], bfr[4];
        #pragma unroll
        for (int m = 0; m < 4; ++m)
            afr[m] = *(const short8*)(As + (wr * 64 + m * 16 + lr) * 32 + kq);
        #pragma unroll
        for (int n = 0; n < 4; ++n)
            bfr[n] = *(const short8*)(Ws + (wc * 64 + n * 16 + lr) * 32 + kq);
        #pragma unroll
        for (int m = 0; m < 4; ++m)
            #pragma unroll
            for (int n = 0; n < 4; ++n)
                acc[m][n] = __builtin_amdgcn_mfma_f32_16x16x32_bf16(
                    afr[m], bfr[n], acc[m][n], 0, 0, 0);
        __syncthreads();
    }

    #pragma unroll
    for (int m = 0; m < 4; ++m) {
        #pragma unroll
        for (int n = 0; n < 4; ++n) {
            int colg = n0 + wc * 64 + n * 16 + (lane & 15);
            #pragma unroll
            for (int r = 0; r < 4; ++r) {
                int rowg = m0 + wr * 64 + m * 16 + (lane >> 4) * 4 + r;
                C[(size_t)rowg * ldc + colg] = f2bf(acc[m][n][r]);
            }
        }
    }
}

// ---------------------------------------------------------------------------
// Fused depthwise conv (K=4) + bias + SiLU, emitting BOTH layouts:
//   xcv  [m][d]   (m = b*L + t)
//   xcvt [d][m]   (natural t order; scan handles bwd reversal on read)
// fwd taps t-3..t (w[q] at row tt+q), bwd taps t..t+3 (w[3-q] at row tt+q)
// ---------------------------------------------------------------------------
__global__ __launch_bounds__(256) void conv_fused_k(
    const ushortT* __restrict__ xc_f, const ushortT* __restrict__ xc_b,
    const float* __restrict__ cwf, const float* __restrict__ cwb,
    const float* __restrict__ cbf, const float* __restrict__ cbb,
    ushortT* __restrict__ xcv_f, ushortT* __restrict__ xcv_b,
    ushortT* __restrict__ xcvt_f, ushortT* __restrict__ xcvt_b)
{
    const int dir = blockIdx.z;
    const ushortT* xc = dir ? xc_b : xc_f;
    const float* cw = dir ? cwb : cwf;
    const float* cb = dir ? cbb : cbf;
    ushortT* xcv  = dir ? xcv_b : xcv_f;
    ushortT* xcvt = dir ? xcvt_b : xcvt_f;

    const int tid = threadIdx.x;
    const int m0 = blockIdx.x * 64;
    const int d0 = blockIdx.y * 64;
    const int b = m0 / L_;
    const int t0 = m0 % L_;
    const int dd = tid & 63;
    const int qr = tid >> 6;

    __shared__ ushortT xt[68][66];
    __shared__ ushortT ot[64][66];

    const int tbase = t0 + (dir ? 0 : -3);
    #pragma unroll 4
    for (int it = 0; it < 17; ++it) {
        int r = it * 4 + qr;
        if (r < 68) {
            int tr = tbase + r;
            ushortT v = 0;
            if (r < 67 && tr >= 0 && tr < L_)
                v = xc[((size_t)b * L_ + tr) * DI_ + d0 + dd];
            xt[r][dd] = v;
        }
    }
    __syncthreads();

    float cwv[4];
    #pragma unroll
    for (int q = 0; q < 4; ++q)
        cwv[q] = dir ? cw[(d0 + dd) * 4 + 3 - q] : cw[(d0 + dd) * 4 + q];
    const float cbv = cb[d0 + dd];

    #pragma unroll 4
    for (int it = 0; it < 16; ++it) {
        int tt = it * 4 + qr;
        float acc = cbv;
        #pragma unroll
        for (int q = 0; q < 4; ++q)
            acc += cwv[q] * bf2f(xt[tt + q][dd]);
        ushortT r16 = f2bf(siluf(acc));
        xcv[(size_t)(m0 + tt) * DI_ + d0 + dd] = r16;
        ot[tt][dd] = r16;
    }
    __syncthreads();

    #pragma unroll 4
    for (int it = 0; it < 16; ++it) {
        int rr = it * 4 + qr;      // d offset
        int cc = dd;               // t offset
        xcvt[(size_t)(d0 + rr) * M_ + m0 + cc] = ot[cc][rr];
    }
}

// ---------------------------------------------------------------------------
// Scan bodies (templated on DIR for static vector indexing).
// Streams dt/xcv from [d][m] natural order; 64B register groups.
// ---------------------------------------------------------------------------
template<int DIR>
__device__ __forceinline__ void scan1_body(
    const ushortT* __restrict__ xcv_t, const ushortT* __restrict__ dt_t,
    const float* __restrict__ dbc, const float* __restrict__ Alog,
    float* __restrict__ aprod, float* __restrict__ hloc,
    float (*Bs)[16], int c, int b, int d, int tid)
{
    const int t0 = c * CL_;
    #pragma unroll
    for (int it = 0; it < CL_ / 16; ++it) {
        int row = it * 16 + (tid >> 4);
        int col = tid & 15;
        int tau = t0 + row;
        int pos = DIR ? (L_ - 1 - tau) : tau;
        Bs[row][col] = dbc[((size_t)b * L_ + pos) * 80 + R_ + col];
    }
    __syncthreads();

    float A2[16];
    #pragma unroll
    for (int s = 0; s < 16; ++s)
        A2[s] = -__expf(Alog[d * S_ + s]) * KSC_;

    const size_t sbase = (size_t)d * M_ + b * L_;
    float h[16];
    #pragma unroll
    for (int s = 0; s < 16; ++s) h[s] = 0.f;
    float sdt = 0.f;

    for (int g = 0; g < CL_ / 32; ++g) {
        const int t0g = t0 + 32 * g;
        const int tb = DIR ? (L_ - 32 - t0g) : t0g;
        const ushortT* dp = dt_t + sbase + tb;
        const ushortT* xp = xcv_t + sbase + tb;
        short8 d8[4], x8[4];
        #pragma unroll
        for (int v = 0; v < 4; ++v) {
            d8[v] = *(const short8*)(dp + v * 8);
            x8[v] = *(const short8*)(xp + v * 8);
        }
        #pragma unroll
        for (int jj = 0; jj < 32; ++jj) {
            const int q = DIR ? (31 - jj) : jj;
            float dtv = bf2f((ushortT)d8[q >> 3][q & 7]);
            float xv  = bf2f((ushortT)x8[q >> 3][q & 7]);
            float bx = dtv * xv;
            sdt += dtv;
            const int row = 32 * g + jj;
            float Bv[16];
            const f32x4* B4 = (const f32x4*)&Bs[row][0];
            *(f32x4*)&Bv[0]  = B4[0]; *(f32x4*)&Bv[4]  = B4[1];
            *(f32x4*)&Bv[8]  = B4[2]; *(f32x4*)&Bv[12] = B4[3];
            #pragma unroll
            for (int s = 0; s < 16; ++s) {
                float a = EXP2F(dtv * A2[s]);
                h[s] = a * h[s] + bx * Bv[s];
            }
        }
    }
    size_t idx = ((((size_t)DIR * B_ + b) * NC_ + c) * DI_ + d) * S_;
    #pragma unroll
    for (int qv = 0; qv < 4; ++qv) {
        f32x4 ap, hl;
        #pragma unroll
        for (int e = 0; e < 4; ++e) {
            ap[e] = EXP2F(A2[qv * 4 + e] * sdt);
            hl[e] = h[qv * 4 + e];
        }
        *(f32x4*)(aprod + idx + qv * 4) = ap;
        *(f32x4*)(hloc  + idx + qv * 4) = hl;
    }
}

__global__ __launch_bounds__(256) void scan1_k(
    const ushortT* __restrict__ xcvt_f, const ushortT* __restrict__ dtt_f,
    const float* __restrict__ dbc_f, const float* __restrict__ Af,
    const ushortT* __restrict__ xcvt_b, const ushortT* __restrict__ dtt_b,
    const float* __restrict__ dbc_b, const float* __restrict__ Ab,
    float* __restrict__ aprod, float* __restrict__ hloc)
{
    __shared__ float Bs[CL_][16];
    const int dir = blockIdx.z / NC_, c = blockIdx.z % NC_;
    const int d = blockIdx.x * 256 + threadIdx.x;
    const int b = blockIdx.y;
    if (dir == 0)
        scan1_body<0>(xcvt_f, dtt_f, dbc_f, Af, aprod, hloc, Bs, c, b, d, threadIdx.x);
    else
        scan1_body<1>(xcvt_b, dtt_b, dbc_b, Ab, aprod, hloc, Bs, c, b, d, threadIdx.x);
}

__global__ __launch_bounds__(256) void scan2_k(
    float* __restrict__ aprod, const float* __restrict__ hloc)
{
    int q = blockIdx.x * 256 + threadIdx.x;
    if (q >= 2 * B_ * DI_ * S_) return;
    int s = q & 15;
    int t = q >> 4;
    int d = t % DI_;
    int t2 = t / DI_;
    int b = t2 & 1, dir = t2 >> 1;
    float h = 0.f;
    for (int c = 0; c < NC_; ++c) {
        size_t idx = ((((size_t)dir * B_ + b) * NC_ + c) * DI_ + d) * S_ + s;
        float a = aprod[idx], hl = hloc[idx];
        aprod[idx] = h;
        h = hl + a * h;
    }
}

template<int DIR>
__device__ __forceinline__ void scan3_body(
    const ushortT* __restrict__ xcv_t, const ushortT* __restrict__ dt_t,
    const float* __restrict__ dbc, const float* __restrict__ Alog,
    ushortT* __restrict__ y_t, const float* __restrict__ hin,
    float (*Bs)[16], float (*Cs)[16], int c, int b, int d, int tid)
{
    const int t0 = c * CL_;
    #pragma unroll
    for (int it = 0; it < CL_ / 16; ++it) {
        int row = it * 16 + (tid >> 4);
        int col = tid & 15;
        int tau = t0 + row;
        int pos = DIR ? (L_ - 1 - tau) : tau;
        size_t base = ((size_t)b * L_ + pos) * 80 + R_;
        Bs[row][col] = dbc[base + col];
        Cs[row][col] = dbc[base + 16 + col];
    }
    __syncthreads();

    float A2[16];
    #pragma unroll
    for (int s = 0; s < 16; ++s)
        A2[s] = -__expf(Alog[d * S_ + s]) * KSC_;

    size_t idx = ((((size_t)DIR * B_ + b) * NC_ + c) * DI_ + d) * S_;
    float h[16];
    #pragma unroll
    for (int qv = 0; qv < 4; ++qv) {
        f32x4 hv = *(const f32x4*)(hin + idx + qv * 4);
        h[qv * 4 + 0] = hv[0]; h[qv * 4 + 1] = hv[1];
        h[qv * 4 + 2] = hv[2]; h[qv * 4 + 3] = hv[3];
    }

    const size_t sbase = (size_t)d * M_ + b * L_;
    union { ushortT u[4]; unsigned long long v; } pk;

    for (int g = 0; g < CL_ / 32; ++g) {
        const int t0g = t0 + 32 * g;
        const int tb = DIR ? (L_ - 32 - t0g) : t0g;
        const ushortT* dp = dt_t + sbase + tb;
        const ushortT* xp = xcv_t + sbase + tb;
        short8 d8[4], x8[4];
        #pragma unroll
        for (int v = 0; v < 4; ++v) {
            d8[v] = *(const short8*)(dp + v * 8);
            x8[v] = *(const short8*)(xp + v * 8);
        }
        #pragma unroll
        for (int jj = 0; jj < 32; ++jj) {
            const int q = DIR ? (31 - jj) : jj;
            float dtv = bf2f((ushortT)d8[q >> 3][q & 7]);
            float xv  = bf2f((ushortT)x8[q >> 3][q & 7]);
            float bx = dtv * xv;
            const int row = 32 * g + jj;
            float Bv[16], Cv[16];
            const f32x4* B4 = (const f32x4*)&Bs[row][0];
            const f32x4* C4 = (const f32x4*)&Cs[row][0];
            *(f32x4*)&Bv[0]  = B4[0]; *(f32x4*)&Bv[4]  = B4[1];
            *(f32x4*)&Bv[8]  = B4[2]; *(f32x4*)&Bv[12] = B4[3];
            *(f32x4*)&Cv[0]  = C4[0]; *(f32x4*)&Cv[4]  = C4[1];
            *(f32x4*)&Cv[8]  = C4[2]; *(f32x4*)&Cv[12] = C4[3];
            float y = 0.f;
            #pragma unroll
            for (int s = 0; s < 16; ++s) {
                float a = EXP2F(dtv * A2[s]);
                h[s] = a * h[s] + bx * Bv[s];
                y += h[s] * Cv[s];
            }
            pk.u[DIR ? (3 - (jj & 3)) : (jj & 3)] = f2bf(y);
            if ((jj & 3) == 3) {
                int tst = DIR ? (L_ - 1 - t0g - jj) : (t0g + jj - 3);
                *(unsigned long long*)(y_t + sbase + tst) = pk.v;
            }
        }
    }
}

__global__ __launch_bounds__(256) void scan3_k(
    const ushortT* __restrict__ xcvt_f, const ushortT* __restrict__ dtt_f,
    const float* __restrict__ dbc_f, const float* __restrict__ Af, ushortT* __restrict__ yt_f,
    const ushortT* __restrict__ xcvt_b, const ushortT* __restrict__ dtt_b,
    const float* __restrict__ dbc_b, const float* __restrict__ Ab, ushortT* __restrict__ yt_b,
    const float* __restrict__ hin)
{
    __shared__ float Bs[CL_][16];
    __shared__ float Cs[CL_][16];
    const int dir = blockIdx.z / NC_, c = blockIdx.z % NC_;
    const int d = blockIdx.x * 256 + threadIdx.x;
    const int b = blockIdx.y;
    if (dir == 0)
        scan3_body<0>(xcvt_f, dtt_f, dbc_f, Af, yt_f, hin, Bs, Cs, c, b, d, threadIdx.x);
    else
        scan3_body<1>(xcvt_b, dtt_b, dbc_b, Ab, yt_b, hin, Bs, Cs, c, b, d, threadIdx.x);
}

// ---------------------------------------------------------------------------
// Gate: yp[m][d] = (y + xv*Dp[d]) * silu(z); y LDS-transposed from y_t [d][m].
// In place over xcv. grid (M/64, DI/64, 2)
// ---------------------------------------------------------------------------
__global__ __launch_bounds__(256) void gate_k(
    const ushortT* __restrict__ y_t_f, const ushortT* __restrict__ y_t_b,
    ushortT* __restrict__ xcv_f, ushortT* __restrict__ xcv_b,
    const ushortT* __restrict__ z_f, const ushortT* __restrict__ z_b,
    const float* __restrict__ Dp_f, const float* __restrict__ Dp_b)
{
    const int dir = blockIdx.z;
    const ushortT* y_t = dir ? y_t_b : y_t_f;
    ushortT* xcv = dir ? xcv_b : xcv_f;
    const ushortT* z = dir ? z_b : z_f;
    const float* Dp = dir ? Dp_b : Dp_f;
    const int tid = threadIdx.x;
    const int m0 = blockIdx.x * 64;
    const int d0 = blockIdx.y * 64;
    const int dd = tid & 63;
    const int qr = tid >> 6;
    __shared__ ushortT ys[64][66];
    #pragma unroll 4
    for (int it = 0; it < 16; ++it) {
        int r = it * 4 + qr;
        ys[r][dd] = y_t[(size_t)(d0 + r) * M_ + m0 + dd];
    }
    __syncthreads();
    const float Dpv = Dp[d0 + dd];
    #pragma unroll 4
    for (int it = 0; it < 16; ++it) {
        int mi = it * 4 + qr;
        size_t xi = (size_t)(m0 + mi) * DI_ + d0 + dd;
        float yv = bf2f(ys[dd][mi]);
        float xv = bf2f(xcv[xi]);
        float zv = bf2f(z[xi]);
        xcv[xi] = f2bf((yv + xv * Dpv) * siluf(zv));
    }
}

// ---------------------------------------------------------------------------
// h = x + acc + proj_b ; LayerNorm over D=768
// ---------------------------------------------------------------------------
__global__ __launch_bounds__(256) void final_ln_k(
    const float* __restrict__ x, const float* __restrict__ acc,
    const float* __restrict__ proj_b, const float* __restrict__ ln_g,
    const float* __restrict__ ln_b, float* __restrict__ out)
{
    const int row = blockIdx.x;
    const size_t base = (size_t)row * D_;
    __shared__ float hbuf[D_];
    __shared__ float wsum[4], wsum2[4];
    float s1 = 0.f, s2 = 0.f;
    for (int n = threadIdx.x; n < D_; n += 256) {
        float h = x[base + n] + acc[base + n] + proj_b[n];
        hbuf[n] = h;
        s1 += h; s2 += h * h;
    }
    #pragma unroll
    for (int off = 32; off; off >>= 1) {
        s1 += __shfl_down(s1, off);
        s2 += __shfl_down(s2, off);
    }
    const int wid = threadIdx.x >> 6;
    if ((threadIdx.x & 63) == 0) { wsum[wid] = s1; wsum2[wid] = s2; }
    __syncthreads();
    if (threadIdx.x == 0) {
        float t1 = wsum[0] + wsum[1] + wsum[2] + wsum[3];
        float t2 = wsum2[0] + wsum2[1] + wsum2[2] + wsum2[3];
        float mu = t1 / D_;
        wsum[0] = mu;
        wsum2[0] = t2 / D_ - mu * mu;
    }
    __syncthreads();
    const float mu = wsum[0];
    const float inv = rsqrtf(wsum2[0] + 1e-5f);
    for (int n = threadIdx.x; n < D_; n += 256) {
        out[base + n] = (hbuf[n] - mu) * inv * ln_g[n] + ln_b[n];
    }
}

// ---------------------------------------------------------------------------
extern "C" void kernel_launch(void* const* d_in, const int* in_sizes, int n_in,
                              void* d_out, int out_size, void* d_ws, size_t ws_size,
                              hipStream_t stream)
{
    const float* x        = (const float*)d_in[0];
    const float* f_in_w   = (const float*)d_in[1];
    const float* f_conv_w = (const float*)d_in[2];
    const float* f_conv_b = (const float*)d_in[3];
    const float* f_xproj  = (const float*)d_in[4];
    const float* f_dt_w   = (const float*)d_in[5];
    const float* f_dt_bv  = (const float*)d_in[6];
    const float* f_A_log  = (const float*)d_in[7];
    const float* f_Dp     = (const float*)d_in[8];
    const float* f_out_w  = (const float*)d_in[9];
    const float* b_in_w   = (const float*)d_in[10];
    const float* b_conv_w = (const float*)d_in[11];
    const float* b_conv_b = (const float*)d_in[12];
    const float* b_xproj  = (const float*)d_in[13];
    const float* b_dt_w   = (const float*)d_in[14];
    const float* b_dt_bv  = (const float*)d_in[15];
    const float* b_A_log  = (const float*)d_in[16];
    const float* b_Dp     = (const float*)d_in[17];
    const float* b_out_w  = (const float*)d_in[18];
    const float* proj_w   = (const float*)d_in[19];
    const float* proj_b   = (const float*)d_in[20];
    const float* ln_g     = (const float*)d_in[21];
    const float* ln_b     = (const float*)d_in[22];
    float* out = (float*)d_out;

    // ---- workspace layout (float units) ----
    const size_t TOKH = (size_t)M_ * DI_ / 2;   // bf16 [M][DI] in float units
    float* p = (float*)d_ws;
    ushortT* xbf       = (ushortT*)p;  p += (size_t)M_ * D_ / 2;
    ushortT* projwbf   = (ushortT*)p;  p += (size_t)D_ * DI_ / 2;
    ushortT* outw_f    = (ushortT*)p;  p += (size_t)D_ * DI_ / 2;
    ushortT* outw_b    = (ushortT*)p;  p += (size_t)D_ * DI_ / 2;
    ushortT* xprojbf_f = (ushortT*)p;  p += (size_t)128 * DI_ / 2;   // 80 rows written, pad garbage (masked)
    ushortT* xprojbf_b = (ushortT*)p;  p += (size_t)128 * DI_ / 2;
    ushortT* dtw_f     = (ushortT*)p;  p += (size_t)DI_ * 64 / 2;
    ushortT* dtw_b     = (ushortT*)p;  p += (size_t)DI_ * 64 / 2;
    ushortT* xc_f      = (ushortT*)p;  p += TOKH;
    ushortT* z_f       = (ushortT*)p;  p += TOKH;
    ushortT* xc_b      = (ushortT*)p;  p += TOKH;
    ushortT* z_b       = (ushortT*)p;  p += TOKH;
    ushortT* xcv_f     = (ushortT*)p;  p += TOKH;
    ushortT* xcv_b     = (ushortT*)p;  p += TOKH;
    ushortT* xcvt_f    = (ushortT*)p;  p += TOKH;
    ushortT* xcvt_b    = (ushortT*)p;  p += TOKH;
    ushortT* dtt_f     = (ushortT*)p;  p += TOKH;
    ushortT* dtt_b     = (ushortT*)p;  p += TOKH;
    float*   dbc_f     = p;            p += (size_t)M_ * 80;
    float*   dbc_b     = p;            p += (size_t)M_ * 80;
    ushortT* dbc48_f   = (ushortT*)p;  p += (size_t)M_ * 64 / 2;
    ushortT* dbc48_b   = (ushortT*)p;  p += (size_t)M_ * 64 / 2;
    float*   aprod     = p;            p += (size_t)2 * B_ * NC_ * DI_ * S_;
    float*   hloc      = p;            p += (size_t)2 * B_ * NC_ * DI_ * S_;
    // aliases (dead-before-reuse):
    ushortT* yt_f   = xc_f;          // xc dead after conv
    ushortT* yt_b   = xc_b;
    ushortT* merged = z_f;           // z dead after gate
    float*   accb   = (float*)z_b;

    dim3 blk(256);

    // ---- 1) mega-convert all fp32 weights/x to bf16 ----
    Segs8 segs;
    segs.s[0] = { x,        xbf,       (long)M_ * D_,    1, 1 };
    segs.s[1] = { proj_w,   projwbf,   (long)D_ * DI_,   1, 1 };
    segs.s[2] = { f_out_w,  outw_f,    (long)D_ * DI_,   1, 1 };
    segs.s[3] = { b_out_w,  outw_b,    (long)D_ * DI_,   1, 1 };
    segs.s[4] = { f_xproj,  xprojbf_f, (long)80 * DI_,   1, 1 };
    segs.s[5] = { b_xproj,  xprojbf_b, (long)80 * DI_,   1, 1 };
    segs.s[6] = { f_dt_w,   dtw_f,     (long)DI_ * 64,  48, 64 };
    segs.s[7] = { b_dt_w,   dtw_b,     (long)DI_ * 64,  48, 64 };
    convert_all_k<<<1024, blk, 0, stream>>>(segs);

    // ---- 2) xz GEMM: xc/z halves, fp32 W staged in-kernel ----
    PW pw;
    pw.A = xbf;
    pw.W[0] = f_in_w; pw.W[1] = f_in_w + (size_t)DI_ * D_;
    pw.W[2] = b_in_w; pw.W[3] = b_in_w + (size_t)DI_ * D_;
    pw.C[0] = xc_f; pw.C[1] = z_f; pw.C[2] = xc_b; pw.C[3] = z_b;
    mfma_wf<<<dim3(12, 32, 4), blk, 0, stream>>>(pw, D_, D_, DI_, M_, D_);

    // ---- 3) conv + SiLU, both layouts ----
    conv_fused_k<<<dim3(M_ / 64, DI_ / 64, 2), blk, 0, stream>>>(
        xc_f, xc_b, f_conv_w, b_conv_w, f_conv_b, b_conv_b,
        xcv_f, xcv_b, xcvt_f, xcvt_b);

    // ---- 4) dbc = xcv @ xproj^T (N=80 pad 128), fp32 ----
    P4 pd;
    pd.A[0] = xcv_f;     pd.A[1] = xcv_b;     pd.A[2] = nullptr; pd.A[3] = nullptr;
    pd.W[0] = xprojbf_f; pd.W[1] = xprojbf_b; pd.W[2] = nullptr; pd.W[3] = nullptr;
    pd.C[0] = dbc_f;     pd.C[1] = dbc_b;     pd.C[2] = nullptr; pd.C[3] = nullptr;
    pd.bias[0] = pd.bias[1] = pd.bias[2] = pd.bias[3] = nullptr;
    mfma_nt<float, true, 0><<<dim3(1, 32, 2), blk, 0, stream>>>(
        pd, DI_, DI_, 80, M_, DI_, 80);

    // ---- 5) pack dbc[:, :48] -> bf16 pad64 ----
    pack48_k<<<512, blk, 0, stream>>>(dbc_f, dbc_b, dbc48_f, dbc48_b);

    // ---- 6) dtt[d][m] = softplus(dtw @ dbc48^T + dt_b[d]) ----
    P4 pt;
    pt.A[0] = dtw_f;   pt.A[1] = dtw_b;   pt.A[2] = nullptr; pt.A[3] = nullptr;
    pt.W[0] = dbc48_f; pt.W[1] = dbc48_b; pt.W[2] = nullptr; pt.W[3] = nullptr;
    pt.C[0] = dtt_f;   pt.C[1] = dtt_b;   pt.C[2] = nullptr; pt.C[3] = nullptr;
    pt.bias[0] = f_dt_bv; pt.bias[1] = b_dt_bv; pt.bias[2] = nullptr; pt.bias[3] = nullptr;
    mfma_nt<ushortT, false, 2><<<dim3(32, 12, 2), blk, 0, stream>>>(
        pt, 64, 64, M_, DI_, 64, M_);

    // ---- 7) chunked selective scan ----
    scan1_k<<<dim3(DI_ / 256, B_, 2 * NC_), blk, 0, stream>>>(
        xcvt_f, dtt_f, dbc_f, f_A_log, xcvt_b, dtt_b, dbc_b, b_A_log, aprod, hloc);
    scan2_k<<<(2 * B_ * DI_ * S_ + 255) / 256, blk, 0, stream>>>(aprod, hloc);
    scan3_k<<<dim3(DI_ / 256, B_, 2 * NC_), blk, 0, stream>>>(
        xcvt_f, dtt_f, dbc_f, f_A_log, yt_f,
        xcvt_b, dtt_b, dbc_b, b_A_log, yt_b, aprod);

    // ---- 8) gate ----
    gate_k<<<dim3(M_ / 64, DI_ / 64, 2), blk, 0, stream>>>(
        yt_f, yt_b, xcv_f, xcv_b, z_f, z_b, f_Dp, b_Dp);

    // ---- 9) merged = [yp_f @ f_out_w^T | yp_b @ b_out_w^T] ----
    P4 pm;
    pm.A[0] = xcv_f;  pm.A[1] = xcv_b;  pm.A[2] = nullptr; pm.A[3] = nullptr;
    pm.W[0] = outw_f; pm.W[1] = outw_b; pm.W[2] = nullptr; pm.W[3] = nullptr;
    pm.C[0] = merged; pm.C[1] = merged + D_; pm.C[2] = nullptr; pm.C[3] = nullptr;
    pm.bias[0] = pm.bias[1] = pm.bias[2] = pm.bias[3] = nullptr;
    mfma_nt<ushortT, false, 0><<<dim3(6, 32, 2), blk, 0, stream>>>(
        pm, DI_, DI_, 2 * D_, M_, DI_, 2 * D_);

    // ---- 10) accb = merged @ proj_w^T ----
    P4 pp;
    pp.A[0] = merged;  pp.A[1] = nullptr; pp.A[2] = nullptr; pp.A[3] = nullptr;
    pp.W[0] = projwbf; pp.W[1] = nullptr; pp.W[2] = nullptr; pp.W[3] = nullptr;
    pp.C[0] = accb;    pp.C[1] = nullptr; pp.C[2] = nullptr; pp.C[3] = nullptr;
    pp.bias[0] = pp.bias[1] = pp.bias[2] = pp.bias[3] = nullptr;
    mfma_nt<float, false, 0><<<dim3(6, 32, 1), blk, 0, stream>>>(
        pp, 2 * D_, 2 * D_, D_, M_, 2 * D_, D_);

    // ---- 11) residual + LayerNorm ----
    final_ln_k<<<M_, blk, 0, stream>>>(x, accb, proj_b, ln_g, ln_b, out);
}

// Round 5
// 361.455 us; speedup vs baseline: 12.2160x; 1.1146x over previous
//
#include <hip/hip_runtime.h>
#include <math.h>

#define B_   2
#define L_   2048
#define D_   768
#define DI_  1536
#define S_   16
#define R_   48
#define M_   (B_*L_)   // 4096 tokens
#define NC_  32        // scan chunks
#define CL_  64        // chunk length

typedef unsigned short ushortT;
typedef __attribute__((ext_vector_type(4))) float f32x4;
typedef __attribute__((ext_vector_type(8))) short short8;

#if __has_builtin(__builtin_amdgcn_exp2f)
#define EXP2F(x) __builtin_amdgcn_exp2f(x)
#define KSC_ 1.4426950408889634f
#else
#define EXP2F(x) __expf(x)
#define KSC_ 1.0f
#endif

__device__ __forceinline__ float siluf(float x) { return x / (1.f + __expf(-x)); }

__device__ __forceinline__ ushortT f2bf(float f) {
    unsigned u = __float_as_uint(f);
    unsigned r = (u + 0x7FFFu + ((u >> 16) & 1u)) >> 16;
    return (ushortT)r;
}
__device__ __forceinline__ float bf2f(ushortT h) {
    return __uint_as_float(((unsigned)h) << 16);
}

__device__ __forceinline__ void stage16(const ushortT* g, ushortT* l) {
    __builtin_amdgcn_global_load_lds(
        (const __attribute__((address_space(1))) unsigned int*)g,
        (__attribute__((address_space(3))) unsigned int*)l, 16, 0, 0);
}

__device__ __forceinline__ void storeC(float* p, float v)   { *p = v; }
__device__ __forceinline__ void storeC(ushortT* p, float v) { *p = f2bf(v); }

// ---------------------------------------------------------------------------
// Mega-convert: 8 segments fp32 -> bf16, with optional strided zero-pad.
// ---------------------------------------------------------------------------
struct Seg { const float* src; ushortT* dst; long n; int use; int out; };
struct Segs8 { Seg s[8]; };

__global__ __launch_bounds__(256) void convert_all_k(Segs8 S)
{
    const long stride = (long)gridDim.x * 256;
    for (int si = 0; si < 8; ++si) {
        Seg sg = S.s[si];
        if (sg.out == 1) {
            for (long i = blockIdx.x * 256L + threadIdx.x; i < sg.n; i += stride)
                sg.dst[i] = f2bf(sg.src[i]);
        } else {
            for (long i = blockIdx.x * 256L + threadIdx.x; i < sg.n; i += stride) {
                int c = (int)(i % sg.out);
                long r = i / sg.out;
                sg.dst[i] = (c < sg.use) ? f2bf(sg.src[r * sg.use + c]) : (ushortT)0;
            }
        }
    }
}

// ---------------------------------------------------------------------------
// Transpose-convert: out_w fp32 [D][DI] -> bf16 [DI][D], both dirs
// ---------------------------------------------------------------------------
__global__ __launch_bounds__(256) void transconv_k(
    const float* __restrict__ of, const float* __restrict__ ob,
    ushortT* __restrict__ tf, ushortT* __restrict__ tb)
{
    const int dir = blockIdx.z;
    const float* in = dir ? ob : of;
    ushortT* outp = dir ? tb : tf;
    __shared__ ushortT tile[64][66];
    const int j0 = blockIdx.x * 64;   // DI dim
    const int i0 = blockIdx.y * 64;   // D dim
    const int tid = threadIdx.x;
    const int dd = tid & 63, qr = tid >> 6;
    #pragma unroll 4
    for (int it = 0; it < 16; ++it) {
        int r = it * 4 + qr;
        tile[r][dd] = f2bf(in[(size_t)(i0 + r) * DI_ + j0 + dd]);
    }
    __syncthreads();
    #pragma unroll 4
    for (int it = 0; it < 16; ++it) {
        int r = it * 4 + qr;
        outp[(size_t)(j0 + r) * D_ + i0 + dd] = tile[dd][r];
    }
}

// ---------------------------------------------------------------------------
// MFMA GEMM (bf16 A, bf16 W): C = A @ W^T, 128x128 tile, BK=32, 4 waves.
// z-slice selects pointer set. EPI 0: plain ; EPI 2: softplus(acc+bias[row])
// ---------------------------------------------------------------------------
struct P4 { const ushortT* A[4]; const ushortT* W[4]; void* C[4]; const float* bias[4]; };

template<typename OutT, int EPI>
__global__ __launch_bounds__(256) void mfma_nt(
    P4 P, int lda, int ldw, int ldc, int M, int K)
{
    __shared__ ushortT As[128 * 32];
    __shared__ ushortT Ws[128 * 32];
    const ushortT* A = P.A[blockIdx.z];
    const ushortT* W = P.W[blockIdx.z];
    OutT* C = (OutT*)P.C[blockIdx.z];
    const float* bias = P.bias[blockIdx.z];
    const int tid = threadIdx.x;
    const int lane = tid & 63, wid = tid >> 6;
    const int wr = wid >> 1, wc = wid & 1;
    const int m0 = blockIdx.y * 128, n0 = blockIdx.x * 128;

    f32x4 acc[4][4];
    #pragma unroll
    for (int m = 0; m < 4; ++m)
        #pragma unroll
        for (int n = 0; n < 4; ++n)
            acc[m][n] = (f32x4){0.f, 0.f, 0.f, 0.f};

    const int kq = (lane >> 4) * 8;
    const int lr = lane & 15;

    for (int k0 = 0; k0 < K; k0 += 32) {
        #pragma unroll
        for (int r = 0; r < 2; ++r) {
            int off = r * 4096 + tid * 16;
            int row = off >> 6;
            int col = (off & 63) >> 1;
            int lbase = r * 2048 + wid * 512;
            stage16(A + (size_t)(m0 + row) * lda + k0 + col, As + lbase);
            stage16(W + (size_t)(n0 + row) * ldw + k0 + col, Ws + lbase);
        }
        __syncthreads();

        short8 afr[4], bfr[4];
        #pragma unroll
        for (int m = 0; m < 4; ++m)
            afr[m] = *(const short8*)(As + (wr * 64 + m * 16 + lr) * 32 + kq);
        #pragma unroll
        for (int n = 0; n < 4; ++n)
            bfr[n] = *(const short8*)(Ws + (wc * 64 + n * 16 + lr) * 32 + kq);
        #pragma unroll
        for (int m = 0; m < 4; ++m)
            #pragma unroll
            for (int n = 0; n < 4; ++n)
                acc[m][n] = __builtin_amdgcn_mfma_f32_16x16x32_bf16(
                    afr[m], bfr[n], acc[m][n], 0, 0, 0);
        __syncthreads();
    }

    #pragma unroll
    for (int m = 0; m < 4; ++m) {
        #pragma unroll
        for (int n = 0; n < 4; ++n) {
            int colg = n0 + wc * 64 + n * 16 + (lane & 15);
            #pragma unroll
            for (int r = 0; r < 4; ++r) {
                int rowg = m0 + wr * 64 + m * 16 + (lane >> 4) * 4 + r;
                float v = acc[m][n][r];
                if (EPI == 2) {
                    v += bias[rowg];
                    v = (v > 20.f) ? v : log1pf(__expf(v));
                }
                storeC(&C[(size_t)rowg * ldc + colg], v);
            }
        }
    }
}

// ---------------------------------------------------------------------------
// dbc split-K GEMM: per z = dir*4+ks, computes 128xM rows x 80 cols partial
// over K slice [ks*384, ks*384+384). A = xcvcat (lda 3072), W = xproj pad128.
// ---------------------------------------------------------------------------
__global__ __launch_bounds__(256) void mfma_dbc_k(
    const ushortT* __restrict__ xcvcat,
    const ushortT* __restrict__ xprj_f, const ushortT* __restrict__ xprj_b,
    float* __restrict__ dbc_part)
{
    __shared__ ushortT As[128 * 32];
    __shared__ ushortT Ws[128 * 32];
    const int z = blockIdx.y;
    const int dir = z >> 2, ks = z & 3;
    const ushortT* A = xcvcat + dir * DI_ + ks * 384;
    const ushortT* W = (dir ? xprj_b : xprj_f) + ks * 384;
    float* C = dbc_part + (size_t)z * M_ * 80;
    const int tid = threadIdx.x;
    const int lane = tid & 63, wid = tid >> 6;
    const int wr = wid >> 1, wc = wid & 1;
    const int m0 = blockIdx.x * 128;

    f32x4 acc[4][4];
    #pragma unroll
    for (int m = 0; m < 4; ++m)
        #pragma unroll
        for (int n = 0; n < 4; ++n)
            acc[m][n] = (f32x4){0.f, 0.f, 0.f, 0.f};

    const int kq = (lane >> 4) * 8;
    const int lr = lane & 15;

    for (int k0 = 0; k0 < 384; k0 += 32) {
        #pragma unroll
        for (int r = 0; r < 2; ++r) {
            int off = r * 4096 + tid * 16;
            int row = off >> 6;
            int col = (off & 63) >> 1;
            int lbase = r * 2048 + wid * 512;
            stage16(A + (size_t)(m0 + row) * 3072 + k0 + col, As + lbase);
            stage16(W + (size_t)row * DI_ + k0 + col, Ws + lbase);
        }
        __syncthreads();

        short8 afr[4], bfr[4];
        #pragma unroll
        for (int m = 0; m < 4; ++m)
            afr[m] = *(const short8*)(As + (wr * 64 + m * 16 + lr) * 32 + kq);
        #pragma unroll
        for (int n = 0; n < 4; ++n)
            bfr[n] = *(const short8*)(Ws + (wc * 64 + n * 16 + lr) * 32 + kq);
        #pragma unroll
        for (int m = 0; m < 4; ++m)
            #pragma unroll
            for (int n = 0; n < 4; ++n)
                acc[m][n] = __builtin_amdgcn_mfma_f32_16x16x32_bf16(
                    afr[m], bfr[n], acc[m][n], 0, 0, 0);
        __syncthreads();
    }

    #pragma unroll
    for (int m = 0; m < 4; ++m) {
        #pragma unroll
        for (int n = 0; n < 4; ++n) {
            int colg = wc * 64 + n * 16 + (lane & 15);
            if (colg >= 80) continue;
            #pragma unroll
            for (int r = 0; r < 4; ++r) {
                int rowg = m0 + wr * 64 + m * 16 + (lane >> 4) * 4 + r;
                C[(size_t)rowg * 80 + colg] = acc[m][n][r];
            }
        }
    }
}

// ---------------------------------------------------------------------------
// Reduce 4 dbc partials -> dbc fp32 [M][80] + dbc48 bf16 [M][64] (pad 0)
// ---------------------------------------------------------------------------
__global__ __launch_bounds__(256) void pack48red_k(
    const float* __restrict__ part,
    float* __restrict__ dbc_f, float* __restrict__ dbc_b,
    ushortT* __restrict__ dbc48_f, ushortT* __restrict__ dbc48_b)
{
    const long n = (long)M_ * 80;
    for (long i = blockIdx.x * 256L + threadIdx.x; i < 2 * n; i += (long)gridDim.x * 256) {
        int dir = (i >= n);
        long j = dir ? i - n : i;
        int col = (int)(j % 80);
        long m = j / 80;
        size_t base = ((size_t)dir * 4 * M_ + m) * 80 + col;
        float sum = part[base] + part[base + (size_t)M_ * 80]
                  + part[base + (size_t)2 * M_ * 80] + part[base + (size_t)3 * M_ * 80];
        (dir ? dbc_b : dbc_f)[m * 80 + col] = sum;
        if (col < 64)
            (dir ? dbc48_b : dbc48_f)[m * 64 + col] = (col < 48) ? f2bf(sum) : (ushortT)0;
    }
}

// ---------------------------------------------------------------------------
// Fused depthwise conv (K=4) + bias + SiLU, emitting BOTH layouts:
//   xcvcat [m][3072] (dir half) and xcvt [d][m]
// ---------------------------------------------------------------------------
__global__ __launch_bounds__(256) void conv_fused_k(
    const ushortT* __restrict__ xc_f, const ushortT* __restrict__ xc_b,
    const float* __restrict__ cwf, const float* __restrict__ cwb,
    const float* __restrict__ cbf, const float* __restrict__ cbb,
    ushortT* __restrict__ xcvcat,
    ushortT* __restrict__ xcvt_f, ushortT* __restrict__ xcvt_b)
{
    const int dir = blockIdx.z;
    const ushortT* xc = dir ? xc_b : xc_f;
    const float* cw = dir ? cwb : cwf;
    const float* cb = dir ? cbb : cbf;
    ushortT* xcvt = dir ? xcvt_b : xcvt_f;
    const int dirOff = dir * DI_;

    const int tid = threadIdx.x;
    const int m0 = blockIdx.x * 64;
    const int d0 = blockIdx.y * 64;
    const int b = m0 / L_;
    const int t0 = m0 % L_;
    const int dd = tid & 63;
    const int qr = tid >> 6;

    __shared__ ushortT xt[68][66];
    __shared__ ushortT ot[64][66];

    const int tbase = t0 + (dir ? 0 : -3);
    #pragma unroll 4
    for (int it = 0; it < 17; ++it) {
        int r = it * 4 + qr;
        if (r < 68) {
            int tr = tbase + r;
            ushortT v = 0;
            if (r < 67 && tr >= 0 && tr < L_)
                v = xc[((size_t)b * L_ + tr) * DI_ + d0 + dd];
            xt[r][dd] = v;
        }
    }
    __syncthreads();

    float cwv[4];
    #pragma unroll
    for (int q = 0; q < 4; ++q)
        cwv[q] = dir ? cw[(d0 + dd) * 4 + 3 - q] : cw[(d0 + dd) * 4 + q];
    const float cbv = cb[d0 + dd];

    #pragma unroll 4
    for (int it = 0; it < 16; ++it) {
        int tt = it * 4 + qr;
        float acc = cbv;
        #pragma unroll
        for (int q = 0; q < 4; ++q)
            acc += cwv[q] * bf2f(xt[tt + q][dd]);
        ushortT r16 = f2bf(siluf(acc));
        xcvcat[(size_t)(m0 + tt) * 3072 + dirOff + d0 + dd] = r16;
        ot[tt][dd] = r16;
    }
    __syncthreads();

    #pragma unroll 4
    for (int it = 0; it < 16; ++it) {
        int rr = it * 4 + qr;
        int cc = dd;
        xcvt[(size_t)(d0 + rr) * M_ + m0 + cc] = ot[cc][rr];
    }
}

// ---------------------------------------------------------------------------
// Scan bodies (templated DIR), streams from [d][m] natural order.
// ---------------------------------------------------------------------------
template<int DIR>
__device__ __forceinline__ void scan1_body(
    const ushortT* __restrict__ xcv_t, const ushortT* __restrict__ dt_t,
    const float* __restrict__ dbc, const float* __restrict__ Alog,
    float* __restrict__ aprod, float* __restrict__ hloc,
    float (*Bs)[16], int c, int b, int d, int tid)
{
    const int t0 = c * CL_;
    #pragma unroll
    for (int it = 0; it < CL_ / 16; ++it) {
        int row = it * 16 + (tid >> 4);
        int col = tid & 15;
        int tau = t0 + row;
        int pos = DIR ? (L_ - 1 - tau) : tau;
        Bs[row][col] = dbc[((size_t)b * L_ + pos) * 80 + R_ + col];
    }
    __syncthreads();

    float A2[16];
    #pragma unroll
    for (int s = 0; s < 16; ++s)
        A2[s] = -__expf(Alog[d * S_ + s]) * KSC_;

    const size_t sbase = (size_t)d * M_ + b * L_;
    float h[16];
    #pragma unroll
    for (int s = 0; s < 16; ++s) h[s] = 0.f;
    float sdt = 0.f;

    for (int g = 0; g < CL_ / 32; ++g) {
        const int t0g = t0 + 32 * g;
        const int tb = DIR ? (L_ - 32 - t0g) : t0g;
        const ushortT* dp = dt_t + sbase + tb;
        const ushortT* xp = xcv_t + sbase + tb;
        short8 d8[4], x8[4];
        #pragma unroll
        for (int v = 0; v < 4; ++v) {
            d8[v] = *(const short8*)(dp + v * 8);
            x8[v] = *(const short8*)(xp + v * 8);
        }
        #pragma unroll
        for (int jj = 0; jj < 32; ++jj) {
            const int q = DIR ? (31 - jj) : jj;
            float dtv = bf2f((ushortT)d8[q >> 3][q & 7]);
            float xv  = bf2f((ushortT)x8[q >> 3][q & 7]);
            float bx = dtv * xv;
            sdt += dtv;
            const int row = 32 * g + jj;
            float Bv[16];
            const f32x4* B4 = (const f32x4*)&Bs[row][0];
            *(f32x4*)&Bv[0]  = B4[0]; *(f32x4*)&Bv[4]  = B4[1];
            *(f32x4*)&Bv[8]  = B4[2]; *(f32x4*)&Bv[12] = B4[3];
            #pragma unroll
            for (int s = 0; s < 16; ++s) {
                float a = EXP2F(dtv * A2[s]);
                h[s] = a * h[s] + bx * Bv[s];
            }
        }
    }
    size_t idx = ((((size_t)DIR * B_ + b) * NC_ + c) * DI_ + d) * S_;
    #pragma unroll
    for (int qv = 0; qv < 4; ++qv) {
        f32x4 ap, hl;
        #pragma unroll
        for (int e = 0; e < 4; ++e) {
            ap[e] = EXP2F(A2[qv * 4 + e] * sdt);
            hl[e] = h[qv * 4 + e];
        }
        *(f32x4*)(aprod + idx + qv * 4) = ap;
        *(f32x4*)(hloc  + idx + qv * 4) = hl;
    }
}

__global__ __launch_bounds__(256) void scan1_k(
    const ushortT* __restrict__ xcvt_f, const ushortT* __restrict__ dtt_f,
    const float* __restrict__ dbc_f, const float* __restrict__ Af,
    const ushortT* __restrict__ xcvt_b, const ushortT* __restrict__ dtt_b,
    const float* __restrict__ dbc_b, const float* __restrict__ Ab,
    float* __restrict__ aprod, float* __restrict__ hloc)
{
    __shared__ float Bs[CL_][16];
    const int dir = blockIdx.z / NC_, c = blockIdx.z % NC_;
    const int d = blockIdx.x * 256 + threadIdx.x;
    const int b = blockIdx.y;
    if (dir == 0)
        scan1_body<0>(xcvt_f, dtt_f, dbc_f, Af, aprod, hloc, Bs, c, b, d, threadIdx.x);
    else
        scan1_body<1>(xcvt_b, dtt_b, dbc_b, Ab, aprod, hloc, Bs, c, b, d, threadIdx.x);
}

__global__ __launch_bounds__(256) void scan2_k(
    float* __restrict__ aprod, const float* __restrict__ hloc)
{
    int q = blockIdx.x * 256 + threadIdx.x;
    if (q >= 2 * B_ * DI_ * S_) return;
    int s = q & 15;
    int t = q >> 4;
    int d = t % DI_;
    int t2 = t / DI_;
    int b = t2 & 1, dir = t2 >> 1;
    float h = 0.f;
    for (int c = 0; c < NC_; ++c) {
        size_t idx = ((((size_t)dir * B_ + b) * NC_ + c) * DI_ + d) * S_ + s;
        float a = aprod[idx], hl = hloc[idx];
        aprod[idx] = h;
        h = hl + a * h;
    }
}

template<int DIR>
__device__ __forceinline__ void scan3_body(
    const ushortT* __restrict__ xcv_t, const ushortT* __restrict__ dt_t,
    const float* __restrict__ dbc, const float* __restrict__ Alog,
    ushortT* __restrict__ y_t, const float* __restrict__ hin,
    float (*Bs)[16], float (*Cs)[16], int c, int b, int d, int tid)
{
    const int t0 = c * CL_;
    #pragma unroll
    for (int it = 0; it < CL_ / 16; ++it) {
        int row = it * 16 + (tid >> 4);
        int col = tid & 15;
        int tau = t0 + row;
        int pos = DIR ? (L_ - 1 - tau) : tau;
        size_t base = ((size_t)b * L_ + pos) * 80 + R_;
        Bs[row][col] = dbc[base + col];
        Cs[row][col] = dbc[base + 16 + col];
    }
    __syncthreads();

    float A2[16];
    #pragma unroll
    for (int s = 0; s < 16; ++s)
        A2[s] = -__expf(Alog[d * S_ + s]) * KSC_;

    size_t idx = ((((size_t)DIR * B_ + b) * NC_ + c) * DI_ + d) * S_;
    float h[16];
    #pragma unroll
    for (int qv = 0; qv < 4; ++qv) {
        f32x4 hv = *(const f32x4*)(hin + idx + qv * 4);
        h[qv * 4 + 0] = hv[0]; h[qv * 4 + 1] = hv[1];
        h[qv * 4 + 2] = hv[2]; h[qv * 4 + 3] = hv[3];
    }

    const size_t sbase = (size_t)d * M_ + b * L_;
    union { ushortT u[4]; unsigned long long v; } pk;

    for (int g = 0; g < CL_ / 32; ++g) {
        const int t0g = t0 + 32 * g;
        const int tb = DIR ? (L_ - 32 - t0g) : t0g;
        const ushortT* dp = dt_t + sbase + tb;
        const ushortT* xp = xcv_t + sbase + tb;
        short8 d8[4], x8[4];
        #pragma unroll
        for (int v = 0; v < 4; ++v) {
            d8[v] = *(const short8*)(dp + v * 8);
            x8[v] = *(const short8*)(xp + v * 8);
        }
        #pragma unroll
        for (int jj = 0; jj < 32; ++jj) {
            const int q = DIR ? (31 - jj) : jj;
            float dtv = bf2f((ushortT)d8[q >> 3][q & 7]);
            float xv  = bf2f((ushortT)x8[q >> 3][q & 7]);
            float bx = dtv * xv;
            const int row = 32 * g + jj;
            float Bv[16], Cv[16];
            const f32x4* B4 = (const f32x4*)&Bs[row][0];
            const f32x4* C4 = (const f32x4*)&Cs[row][0];
            *(f32x4*)&Bv[0]  = B4[0]; *(f32x4*)&Bv[4]  = B4[1];
            *(f32x4*)&Bv[8]  = B4[2]; *(f32x4*)&Bv[12] = B4[3];
            *(f32x4*)&Cv[0]  = C4[0]; *(f32x4*)&Cv[4]  = C4[1];
            *(f32x4*)&Cv[8]  = C4[2]; *(f32x4*)&Cv[12] = C4[3];
            float y = 0.f;
            #pragma unroll
            for (int s = 0; s < 16; ++s) {
                float a = EXP2F(dtv * A2[s]);
                h[s] = a * h[s] + bx * Bv[s];
                y += h[s] * Cv[s];
            }
            pk.u[DIR ? (3 - (jj & 3)) : (jj & 3)] = f2bf(y);
            if ((jj & 3) == 3) {
                int tst = DIR ? (L_ - 1 - t0g - jj) : (t0g + jj - 3);
                *(unsigned long long*)(y_t + sbase + tst) = pk.v;
            }
        }
    }
}

__global__ __launch_bounds__(256) void scan3_k(
    const ushortT* __restrict__ xcvt_f, const ushortT* __restrict__ dtt_f,
    const float* __restrict__ dbc_f, const float* __restrict__ Af, ushortT* __restrict__ yt_f,
    const ushortT* __restrict__ xcvt_b, const ushortT* __restrict__ dtt_b,
    const float* __restrict__ dbc_b, const float* __restrict__ Ab, ushortT* __restrict__ yt_b,
    const float* __restrict__ hin)
{
    __shared__ float Bs[CL_][16];
    __shared__ float Cs[CL_][16];
    const int dir = blockIdx.z / NC_, c = blockIdx.z % NC_;
    const int d = blockIdx.x * 256 + threadIdx.x;
    const int b = blockIdx.y;
    if (dir == 0)
        scan3_body<0>(xcvt_f, dtt_f, dbc_f, Af, yt_f, hin, Bs, Cs, c, b, d, threadIdx.x);
    else
        scan3_body<1>(xcvt_b, dtt_b, dbc_b, Ab, yt_b, hin, Bs, Cs, c, b, d, threadIdx.x);
}

// ---------------------------------------------------------------------------
// Gate: yp = (y + xv*Dp)*silu(z) written into xcvcat (stride 3072) in place.
// ---------------------------------------------------------------------------
__global__ __launch_bounds__(256) void gate_k(
    const ushortT* __restrict__ y_t_f, const ushortT* __restrict__ y_t_b,
    ushortT* __restrict__ xcvcat,
    const ushortT* __restrict__ z_f, const ushortT* __restrict__ z_b,
    const float* __restrict__ Dp_f, const float* __restrict__ Dp_b)
{
    const int dir = blockIdx.z;
    const ushortT* y_t = dir ? y_t_b : y_t_f;
    const ushortT* z = dir ? z_b : z_f;
    const float* Dp = dir ? Dp_b : Dp_f;
    const int dirOff = dir * DI_;
    const int tid = threadIdx.x;
    const int m0 = blockIdx.x * 64;
    const int d0 = blockIdx.y * 64;
    const int dd = tid & 63;
    const int qr = tid >> 6;
    __shared__ ushortT ys[64][66];
    #pragma unroll 4
    for (int it = 0; it < 16; ++it) {
        int r = it * 4 + qr;
        ys[r][dd] = y_t[(size_t)(d0 + r) * M_ + m0 + dd];
    }
    __syncthreads();
    const float Dpv = Dp[d0 + dd];
    #pragma unroll 4
    for (int it = 0; it < 16; ++it) {
        int mi = it * 4 + qr;
        size_t zi = (size_t)(m0 + mi) * DI_ + d0 + dd;
        size_t xi = (size_t)(m0 + mi) * 3072 + dirOff + d0 + dd;
        float yv = bf2f(ys[dd][mi]);
        float xv = bf2f(xcvcat[xi]);
        float zv = bf2f(z[zi]);
        xcvcat[xi] = f2bf((yv + xv * Dpv) * siluf(zv));
    }
}

// ---------------------------------------------------------------------------
// h = x + acc0 + acc1 + proj_b ; LayerNorm over D=768
// ---------------------------------------------------------------------------
__global__ __launch_bounds__(256) void final_ln_k(
    const float* __restrict__ x, const float* __restrict__ acc0,
    const float* __restrict__ acc1,
    const float* __restrict__ proj_b, const float* __restrict__ ln_g,
    const float* __restrict__ ln_b, float* __restrict__ out)
{
    const int row = blockIdx.x;
    const size_t base = (size_t)row * D_;
    __shared__ float hbuf[D_];
    __shared__ float wsum[4], wsum2[4];
    float s1 = 0.f, s2 = 0.f;
    for (int n = threadIdx.x; n < D_; n += 256) {
        float h = x[base + n] + acc0[base + n] + acc1[base + n] + proj_b[n];
        hbuf[n] = h;
        s1 += h; s2 += h * h;
    }
    #pragma unroll
    for (int off = 32; off; off >>= 1) {
        s1 += __shfl_down(s1, off);
        s2 += __shfl_down(s2, off);
    }
    const int wid = threadIdx.x >> 6;
    if ((threadIdx.x & 63) == 0) { wsum[wid] = s1; wsum2[wid] = s2; }
    __syncthreads();
    if (threadIdx.x == 0) {
        float t1 = wsum[0] + wsum[1] + wsum[2] + wsum[3];
        float t2 = wsum2[0] + wsum2[1] + wsum2[2] + wsum2[3];
        float mu = t1 / D_;
        wsum[0] = mu;
        wsum2[0] = t2 / D_ - mu * mu;
    }
    __syncthreads();
    const float mu = wsum[0];
    const float inv = rsqrtf(wsum2[0] + 1e-5f);
    for (int n = threadIdx.x; n < D_; n += 256) {
        out[base + n] = (hbuf[n] - mu) * inv * ln_g[n] + ln_b[n];
    }
}

// ---------------------------------------------------------------------------
extern "C" void kernel_launch(void* const* d_in, const int* in_sizes, int n_in,
                              void* d_out, int out_size, void* d_ws, size_t ws_size,
                              hipStream_t stream)
{
    const float* x        = (const float*)d_in[0];
    const float* f_in_w   = (const float*)d_in[1];
    const float* f_conv_w = (const float*)d_in[2];
    const float* f_conv_b = (const float*)d_in[3];
    const float* f_xproj  = (const float*)d_in[4];
    const float* f_dt_w   = (const float*)d_in[5];
    const float* f_dt_bv  = (const float*)d_in[6];
    const float* f_A_log  = (const float*)d_in[7];
    const float* f_Dp     = (const float*)d_in[8];
    const float* f_out_w  = (const float*)d_in[9];
    const float* b_in_w   = (const float*)d_in[10];
    const float* b_conv_w = (const float*)d_in[11];
    const float* b_conv_b = (const float*)d_in[12];
    const float* b_xproj  = (const float*)d_in[13];
    const float* b_dt_w   = (const float*)d_in[14];
    const float* b_dt_bv  = (const float*)d_in[15];
    const float* b_A_log  = (const float*)d_in[16];
    const float* b_Dp     = (const float*)d_in[17];
    const float* b_out_w  = (const float*)d_in[18];
    const float* proj_w   = (const float*)d_in[19];
    const float* proj_b   = (const float*)d_in[20];
    const float* ln_g     = (const float*)d_in[21];
    const float* ln_b     = (const float*)d_in[22];
    float* out = (float*)d_out;

    // ---- workspace layout (float units) ----
    const size_t TOKH = (size_t)M_ * DI_ / 2;
    float* p = (float*)d_ws;
    ushortT* xbf       = (ushortT*)p;  p += (size_t)M_ * D_ / 2;
    ushortT* projwbf   = (ushortT*)p;  p += (size_t)D_ * DI_ / 2;
    ushortT* inwbf_f   = (ushortT*)p;  p += (size_t)2 * DI_ * D_ / 2;   // later: Wccat [768][3072]
    ushortT* inwbf_b   = (ushortT*)p;  p += (size_t)2 * DI_ * D_ / 2;   // later: outwT f+b
    ushortT* xprojbf_f = (ushortT*)p;  p += (size_t)128 * DI_ / 2;      // 80 rows valid, pad garbage (masked)
    ushortT* xprojbf_b = (ushortT*)p;  p += (size_t)128 * DI_ / 2;
    ushortT* dtw_f     = (ushortT*)p;  p += (size_t)DI_ * 64 / 2;
    ushortT* dtw_b     = (ushortT*)p;  p += (size_t)DI_ * 64 / 2;
    ushortT* xc_f      = (ushortT*)p;  p += TOKH;
    ushortT* z_f       = (ushortT*)p;  p += TOKH;
    ushortT* xc_b      = (ushortT*)p;  p += TOKH;
    ushortT* z_b       = (ushortT*)p;  p += TOKH;
    ushortT* xcvcat    = (ushortT*)p;  p += (size_t)M_ * 3072 / 2;
    ushortT* xcvt_f    = (ushortT*)p;  p += TOKH;
    ushortT* xcvt_b    = (ushortT*)p;  p += TOKH;
    ushortT* dtt_f     = (ushortT*)p;  p += TOKH;
    ushortT* dtt_b     = (ushortT*)p;  p += TOKH;
    float*   dbc_f     = p;            p += (size_t)M_ * 80;
    float*   dbc_b     = p;            p += (size_t)M_ * 80;
    ushortT* dbc48_f   = (ushortT*)p;  p += (size_t)M_ * 64 / 2;
    ushortT* dbc48_b   = (ushortT*)p;  p += (size_t)M_ * 64 / 2;
    float*   aprod     = p;            p += (size_t)2 * B_ * NC_ * DI_ * S_;
    float*   hloc      = p;            p += (size_t)2 * B_ * NC_ * DI_ * S_;
    // aliases (dead-before-reuse, stream-ordered):
    ushortT* Wccat   = inwbf_f;            // [768][3072], written after in_w consumed
    ushortT* outwT_f = inwbf_b;            // [1536][768]
    ushortT* outwT_b = inwbf_b + (size_t)DI_ * D_;
    float*   dbc_part = aprod;             // [8][M][80] inside aprod region
    ushortT* yt_f   = xc_f;                // xc dead after conv
    ushortT* yt_b   = xc_b;
    float*   accb0  = (float*)z_b;         // z dead after gate
    float*   accb1  = (float*)z_f;

    dim3 blk(256);

    // ---- 1) mega-convert fp32 -> bf16 ----
    Segs8 segs;
    segs.s[0] = { x,        xbf,       (long)M_ * D_,      1, 1 };
    segs.s[1] = { proj_w,   projwbf,   (long)D_ * DI_,     1, 1 };
    segs.s[2] = { f_xproj,  xprojbf_f, (long)80 * DI_,     1, 1 };
    segs.s[3] = { b_xproj,  xprojbf_b, (long)80 * DI_,     1, 1 };
    segs.s[4] = { f_dt_w,   dtw_f,     (long)DI_ * 64,    48, 64 };
    segs.s[5] = { b_dt_w,   dtw_b,     (long)DI_ * 64,    48, 64 };
    segs.s[6] = { f_in_w,   inwbf_f,   (long)2 * DI_ * D_, 1, 1 };
    segs.s[7] = { b_in_w,   inwbf_b,   (long)2 * DI_ * D_, 1, 1 };
    convert_all_k<<<1024, blk, 0, stream>>>(segs);

    // ---- 2) xz GEMM (4 halves) ----
    P4 px;
    px.A[0] = px.A[1] = px.A[2] = px.A[3] = xbf;
    px.W[0] = inwbf_f; px.W[1] = inwbf_f + (size_t)DI_ * D_;
    px.W[2] = inwbf_b; px.W[3] = inwbf_b + (size_t)DI_ * D_;
    px.C[0] = xc_f; px.C[1] = z_f; px.C[2] = xc_b; px.C[3] = z_b;
    px.bias[0] = px.bias[1] = px.bias[2] = px.bias[3] = nullptr;
    mfma_nt<ushortT, 0><<<dim3(12, 32, 4), blk, 0, stream>>>(
        px, D_, D_, DI_, M_, D_);

    // ---- 3) out_w transpose-convert (into dead inwbf_b region) ----
    transconv_k<<<dim3(24, 12, 2), blk, 0, stream>>>(f_out_w, b_out_w, outwT_f, outwT_b);

    // ---- 4) Wc = proj_slice @ out_w  -> Wccat [768][3072] (dead inwbf_f) ----
    P4 pc;
    pc.A[0] = projwbf;       pc.A[1] = projwbf + D_;
    pc.W[0] = outwT_f;       pc.W[1] = outwT_b;
    pc.C[0] = Wccat;         pc.C[1] = Wccat + DI_;
    pc.A[2] = pc.A[3] = nullptr; pc.W[2] = pc.W[3] = nullptr;
    pc.C[2] = pc.C[3] = nullptr;
    pc.bias[0] = pc.bias[1] = pc.bias[2] = pc.bias[3] = nullptr;
    mfma_nt<ushortT, 0><<<dim3(12, 6, 2), blk, 0, stream>>>(
        pc, 2 * D_, D_, 3072, D_, D_);

    // ---- 5) conv + SiLU, both layouts ----
    conv_fused_k<<<dim3(M_ / 64, DI_ / 64, 2), blk, 0, stream>>>(
        xc_f, xc_b, f_conv_w, b_conv_w, f_conv_b, b_conv_b,
        xcvcat, xcvt_f, xcvt_b);

    // ---- 6) dbc split-K GEMM -> partials ----
    mfma_dbc_k<<<dim3(32, 8), blk, 0, stream>>>(xcvcat, xprojbf_f, xprojbf_b, dbc_part);

    // ---- 7) reduce partials -> dbc fp32 + dbc48 bf16 ----
    pack48red_k<<<1024, blk, 0, stream>>>(dbc_part, dbc_f, dbc_b, dbc48_f, dbc48_b);

    // ---- 8) dtt[d][m] = softplus(dtw @ dbc48^T + dt_b[d]) ----
    P4 pt;
    pt.A[0] = dtw_f;   pt.A[1] = dtw_b;
    pt.W[0] = dbc48_f; pt.W[1] = dbc48_b;
    pt.C[0] = dtt_f;   pt.C[1] = dtt_b;
    pt.A[2] = pt.A[3] = nullptr; pt.W[2] = pt.W[3] = nullptr;
    pt.C[2] = pt.C[3] = nullptr;
    pt.bias[0] = f_dt_bv; pt.bias[1] = b_dt_bv; pt.bias[2] = pt.bias[3] = nullptr;
    mfma_nt<ushortT, 2><<<dim3(32, 12, 2), blk, 0, stream>>>(
        pt, 64, 64, M_, DI_, 64);

    // ---- 9) chunked selective scan ----
    scan1_k<<<dim3(DI_ / 256, B_, 2 * NC_), blk, 0, stream>>>(
        xcvt_f, dtt_f, dbc_f, f_A_log, xcvt_b, dtt_b, dbc_b, b_A_log, aprod, hloc);
    scan2_k<<<(2 * B_ * DI_ * S_ + 255) / 256, blk, 0, stream>>>(aprod, hloc);
    scan3_k<<<dim3(DI_ / 256, B_, 2 * NC_), blk, 0, stream>>>(
        xcvt_f, dtt_f, dbc_f, f_A_log, yt_f,
        xcvt_b, dtt_b, dbc_b, b_A_log, yt_b, aprod);

    // ---- 10) gate (in place over xcvcat) ----
    gate_k<<<dim3(M_ / 64, DI_ / 64, 2), blk, 0, stream>>>(
        yt_f, yt_b, xcvcat, z_f, z_b, f_Dp, b_Dp);

    // ---- 11) accb = yp_cat @ Wccat^T, split-K x2 ----
    P4 pf;
    pf.A[0] = xcvcat;        pf.A[1] = xcvcat + DI_;
    pf.W[0] = Wccat;         pf.W[1] = Wccat + DI_;
    pf.C[0] = accb0;         pf.C[1] = accb1;
    pf.A[2] = pf.A[3] = nullptr; pf.W[2] = pf.W[3] = nullptr;
    pf.C[2] = pf.C[3] = nullptr;
    pf.bias[0] = pf.bias[1] = pf.bias[2] = pf.bias[3] = nullptr;
    mfma_nt<float, 0><<<dim3(6, 32, 2), blk, 0, stream>>>(
        pf, 3072, 3072, D_, M_, DI_);

    // ---- 12) residual + LayerNorm ----
    final_ln_k<<<M_, blk, 0, stream>>>(x, accb0, accb1, proj_b, ln_g, ln_b, out);
}